// Round 6
// baseline (995.731 us; speedup 1.0000x reference)
//
#include <hip/hip_runtime.h>
#include <math.h>

#define NN 100000
#define NX 8   // XCDs (measured: learn_hip m09)

// ---------------- ws layout (bytes) ----------------
// tier A (replica scatter, needs 22.0 MB; known ws >= 23.2 MB):
#define O_FLAG  0
#define O_DINV  256
#define O_XS    400256            // float4[NN]
#define O_HS2   2000256           // float2[NN]
#define O_CNTX  2800256           // u32[NX][NN]    3.2 MB
#define O_AG1   6000256           // float3[NX][NN] 9.6 MB
#define O_AG2   15600256          // float2[NX][NN] 6.4 MB
#define SZ_A    22000256
// tier B (CSR mid path, 16.8 MB) reuses R4 offsets:
#define B_CNT   256
#define B_OFF   400256
#define B_CUR   800256
#define B_DINV  1200256
#define B_CSUM  1600256
#define B_CBASE 1601280
#define B_XS    1602560
#define B_HS2   3202560
#define B_RIDX  4002560
#define SZ_B    16802560
#define CHUNK 1024
#define NCHUNK 98

__device__ __forceinline__ int xcc_id() {
    int x;
    asm volatile("s_getreg_b32 %0, hwreg(HW_REG_XCC_ID)" : "=s"(x));
    return x & (NX - 1);
}
// No sc1 -> RMW executes in the issuing XCD's own L2 (replica is XCD-exclusive).
__device__ __forceinline__ void atom_add_u32_local(unsigned* p, unsigned v) {
    asm volatile("global_atomic_add %0, %1, off" :: "v"(p), "v"(v) : "memory");
}
__device__ __forceinline__ void atom_add_f32_local(float* p, float v) {
    asm volatile("global_atomic_add_f32 %0, %1, off" :: "v"(p), "v"(v) : "memory");
}
__device__ __forceinline__ void drain_vmem() {
    asm volatile("s_waitcnt vmcnt(0)" ::: "memory");
}

__global__ void k_detect(const void* ei, int* flag) {
    if (blockIdx.x == 0 && threadIdx.x == 0) {
        const long long* p = (const long long*)ei;
        int ok = 1;
        for (int i = 0; i < 64; ++i) {
            long long v = p[i];
            if (v < 0 || v >= NN) { ok = 0; break; }
        }
        *flag = ok;
    }
}

__global__ void k_zero(float4* z, long long n4) {
    long long stride = (long long)gridDim.x * blockDim.x;
    for (long long i = (long long)blockIdx.x * blockDim.x + threadIdx.x; i < n4; i += stride)
        z[i] = make_float4(0.f, 0.f, 0.f, 0.f);
}

// ---------------- tier A: per-XCD replica scatter ----------------
template <typename T>
__device__ __forceinline__ void degA_loop(const T* __restrict__ col, long long E,
                                          unsigned* __restrict__ cnt) {
    long long stride = (long long)gridDim.x * blockDim.x;
    for (long long e = (long long)blockIdx.x * blockDim.x + threadIdx.x; e < E; e += stride)
        atom_add_u32_local(&cnt[(unsigned)col[e]], 1u);
    drain_vmem();
}
__global__ void k_degA(const void* ei, long long E, const int* flag, unsigned* cntX) {
    unsigned* cnt = cntX + (size_t)xcc_id() * NN;
    if (*flag) degA_loop(((const long long*)ei) + E, E, cnt);
    else       degA_loop(((const int*)ei) + E, E, cnt);
}

__global__ void k_prepA(const float* __restrict__ x, const unsigned* __restrict__ cntX,
                        float* __restrict__ dinv, float4* __restrict__ xs) {
    int i = blockIdx.x * blockDim.x + threadIdx.x;
    if (i >= NN) return;
    unsigned s = 1u;                       // self-loop
#pragma unroll
    for (int k = 0; k < NX; ++k) s += cntX[(size_t)k * NN + i];
    float d = rsqrtf((float)s);
    dinv[i] = d;
    xs[i] = make_float4(x[3*i] * d, x[3*i+1] * d, x[3*i+2] * d, 0.f);
}

template <typename T>
__device__ __forceinline__ void sc1A_loop(const T* __restrict__ ei, long long E,
                                          const float4* __restrict__ xs, float* __restrict__ agg) {
    long long stride = (long long)gridDim.x * blockDim.x;
    for (long long e = (long long)blockIdx.x * blockDim.x + threadIdx.x; e < E; e += stride) {
        unsigned r = (unsigned)ei[e];
        unsigned c = (unsigned)ei[E + e];
        float4 v = xs[r];
        float* p = agg + (size_t)c * 3;
        atom_add_f32_local(p,     v.x);
        atom_add_f32_local(p + 1, v.y);
        atom_add_f32_local(p + 2, v.z);
    }
    drain_vmem();
}
__global__ void k_sc1A(const void* ei, long long E, const int* flag,
                       const float4* __restrict__ xs, float* agg1X) {
    float* agg = agg1X + (size_t)xcc_id() * NN * 3;
    if (*flag) sc1A_loop((const long long*)ei, E, xs, agg);
    else       sc1A_loop((const int*)ei, E, xs, agg);
}

__global__ void k_layerA(const float* __restrict__ W1, const float* __restrict__ b1,
                         const float* __restrict__ W2, const float* __restrict__ dinv,
                         const float4* __restrict__ xs, const float* __restrict__ agg1X,
                         float2* __restrict__ hs2) {
    int i = blockIdx.x * blockDim.x + threadIdx.x;
    if (i >= NN) return;
    float4 s = xs[i];
    float a0 = s.x, a1 = s.y, a2 = s.z;
#pragma unroll
    for (int k = 0; k < NX; ++k) {
        const float* p = agg1X + ((size_t)k * NN + i) * 3;
        a0 += p[0]; a1 += p[1]; a2 += p[2];
    }
    float d = dinv[i];
    float t0 = d * a0, t1 = d * a1, t2 = d * a2;
    float g0 = 0.f, g1 = 0.f;
#pragma unroll
    for (int j = 0; j < 16; ++j) {
        float h = fmaxf(fmaf(t0, W1[j], fmaf(t1, W1[16+j], fmaf(t2, W1[32+j], b1[j]))), 0.f);
        g0 = fmaf(h, W2[2*j],   g0);
        g1 = fmaf(h, W2[2*j+1], g1);
    }
    hs2[i] = make_float2(g0 * d, g1 * d);
}

template <typename T>
__device__ __forceinline__ void sc2A_loop(const T* __restrict__ ei, long long E,
                                          const float2* __restrict__ hs2, float* __restrict__ agg) {
    long long stride = (long long)gridDim.x * blockDim.x;
    for (long long e = (long long)blockIdx.x * blockDim.x + threadIdx.x; e < E; e += stride) {
        unsigned r = (unsigned)ei[e];
        unsigned c = (unsigned)ei[E + e];
        float2 v = hs2[r];
        float* p = agg + (size_t)c * 2;
        atom_add_f32_local(p,     v.x);
        atom_add_f32_local(p + 1, v.y);
    }
    drain_vmem();
}
__global__ void k_sc2A(const void* ei, long long E, const int* flag,
                       const float2* __restrict__ hs2, float* agg2X) {
    float* agg = agg2X + (size_t)xcc_id() * NN * 2;
    if (*flag) sc2A_loop((const long long*)ei, E, hs2, agg);
    else       sc2A_loop((const int*)ei, E, hs2, agg);
}

__global__ void k_outA(const float* __restrict__ b2, const float* __restrict__ dinv,
                       const float2* __restrict__ hs2, const float* __restrict__ agg2X,
                       float2* __restrict__ out) {
    int i = blockIdx.x * blockDim.x + threadIdx.x;
    if (i >= NN) return;
    float2 s = hs2[i];
    float a0 = s.x, a1 = s.y;
#pragma unroll
    for (int k = 0; k < NX; ++k) {
        const float* p = agg2X + ((size_t)k * NN + i) * 2;
        a0 += p[0]; a1 += p[1];
    }
    float d = dinv[i];
    float z0 = d * a0 + b2[0];
    float z1 = d * a1 + b2[1];
    float mx = fmaxf(z0, z1);
    float l  = mx + logf(expf(z0 - mx) + expf(z1 - mx));
    out[i] = make_float2(z0 - l, z1 - l);
}

// ---------------- tier B: CSR mid path (R4 design, known-correct) ----------------
template <typename T>
__device__ __forceinline__ void hist_loop(const T* __restrict__ col, long long E,
                                          unsigned* __restrict__ cnt) {
    long long stride = (long long)gridDim.x * blockDim.x;
    for (long long e = (long long)blockIdx.x * blockDim.x + threadIdx.x; e < E; e += stride)
        atomicAdd(&cnt[(unsigned)col[e]], 1u);
}
__global__ void k_histM(const void* ei, long long E, const int* flag, unsigned* cnt) {
    if (*flag) hist_loop(((const long long*)ei) + E, E, cnt);
    else       hist_loop(((const int*)ei) + E, E, cnt);
}
__global__ void k_scan1(const unsigned* __restrict__ cnt, unsigned* __restrict__ off,
                        unsigned* __restrict__ csum) {
    __shared__ unsigned lds[256];
    int t = threadIdx.x;
    int base = blockIdx.x * CHUNK + t * 4;
    unsigned v[4];
#pragma unroll
    for (int k = 0; k < 4; ++k) { int i = base + k; v[k] = (i < NN) ? cnt[i] : 0u; }
    unsigned s = v[0] + v[1] + v[2] + v[3];
    lds[t] = s; __syncthreads();
    for (int o = 1; o < 256; o <<= 1) {
        unsigned add = (t >= o) ? lds[t - o] : 0u; __syncthreads();
        lds[t] += add; __syncthreads();
    }
    unsigned excl = lds[t] - s;
    if (t == 255) csum[blockIdx.x] = lds[255];
#pragma unroll
    for (int k = 0; k < 4; ++k) { int i = base + k; if (i < NN) off[i] = excl; excl += v[k]; }
}
__global__ void k_scan2(unsigned* __restrict__ csum, unsigned* __restrict__ cbase) {
    __shared__ unsigned lds[256];
    int t = threadIdx.x;
    unsigned s = (t < NCHUNK) ? csum[t] : 0u;
    lds[t] = s; __syncthreads();
    for (int o = 1; o < 256; o <<= 1) {
        unsigned add = (t >= o) ? lds[t - o] : 0u; __syncthreads();
        lds[t] += add; __syncthreads();
    }
    if (t < NCHUNK) cbase[t] = lds[t] - s;
}
__global__ void k_scan3(const unsigned* __restrict__ cnt, const unsigned* __restrict__ cbase,
                        unsigned* __restrict__ off, unsigned* __restrict__ cur,
                        const float* __restrict__ x, float* __restrict__ dinv,
                        float4* __restrict__ xs) {
    int i = blockIdx.x * blockDim.x + threadIdx.x;
    if (i >= NN) return;
    unsigned o = off[i] + cbase[i >> 10];
    off[i] = o; cur[i] = o;
    float d = rsqrtf((float)cnt[i] + 1.0f);
    dinv[i] = d;
    xs[i] = make_float4(x[3*i] * d, x[3*i+1] * d, x[3*i+2] * d, 0.f);
}
template <typename T>
__device__ __forceinline__ void placeM_loop(const T* __restrict__ ei, long long E,
                                            unsigned* __restrict__ cur, unsigned* __restrict__ ridx) {
    long long stride = (long long)gridDim.x * blockDim.x;
    for (long long e = (long long)blockIdx.x * blockDim.x + threadIdx.x; e < E; e += stride) {
        unsigned c = (unsigned)ei[E + e];
        unsigned pos = atomicAdd(&cur[c], 1u);
        ridx[pos] = (unsigned)ei[e];
    }
}
__global__ void k_placeM(const void* ei, long long E, const int* flag,
                         unsigned* cur, unsigned* ridx) {
    if (*flag) placeM_loop((const long long*)ei, E, cur, ridx);
    else       placeM_loop((const int*)ei, E, cur, ridx);
}
__global__ void k_lay1(const unsigned* __restrict__ off, const unsigned* __restrict__ cnt,
                       const unsigned* __restrict__ ridx, const float4* __restrict__ xs,
                       const float* __restrict__ dinv,
                       const float* __restrict__ W1, const float* __restrict__ b1,
                       const float* __restrict__ W2, float2* __restrict__ hs2) {
    int lane = threadIdx.x & 15;
    int node = blockIdx.x * (blockDim.x >> 4) + (threadIdx.x >> 4);
    if (node >= NN) return;
    unsigned s = off[node], n = cnt[node];
    float a0 = 0.f, a1 = 0.f, a2 = 0.f;
    for (unsigned k = lane; k < n; k += 16) {
        float4 v = xs[ridx[s + k]];
        a0 += v.x; a1 += v.y; a2 += v.z;
    }
#pragma unroll
    for (int m = 8; m; m >>= 1) {
        a0 += __shfl_xor(a0, m); a1 += __shfl_xor(a1, m); a2 += __shfl_xor(a2, m);
    }
    if (lane == 0) {
        float4 sv = xs[node];
        float d = dinv[node];
        float t0 = d*(a0+sv.x), t1 = d*(a1+sv.y), t2 = d*(a2+sv.z);
        float g0 = 0.f, g1 = 0.f;
#pragma unroll
        for (int j = 0; j < 16; ++j) {
            float h = fmaxf(fmaf(t0, W1[j], fmaf(t1, W1[16+j], fmaf(t2, W1[32+j], b1[j]))), 0.f);
            g0 = fmaf(h, W2[2*j],   g0);
            g1 = fmaf(h, W2[2*j+1], g1);
        }
        hs2[node] = make_float2(g0 * d, g1 * d);
    }
}
__global__ void k_lay2(const unsigned* __restrict__ off, const unsigned* __restrict__ cnt,
                       const unsigned* __restrict__ ridx, const float2* __restrict__ hs2,
                       const float* __restrict__ dinv, const float* __restrict__ b2,
                       float2* __restrict__ out) {
    int lane = threadIdx.x & 15;
    int node = blockIdx.x * (blockDim.x >> 4) + (threadIdx.x >> 4);
    if (node >= NN) return;
    unsigned s = off[node], n = cnt[node];
    float a0 = 0.f, a1 = 0.f;
    for (unsigned k = lane; k < n; k += 16) {
        float2 v = hs2[ridx[s + k]];
        a0 += v.x; a1 += v.y;
    }
#pragma unroll
    for (int m = 8; m; m >>= 1) {
        a0 += __shfl_xor(a0, m); a1 += __shfl_xor(a1, m);
    }
    if (lane == 0) {
        float2 sv = hs2[node];
        float d = dinv[node];
        float z0 = d*(a0+sv.x) + b2[0];
        float z1 = d*(a1+sv.y) + b2[1];
        float mx = fmaxf(z0, z1);
        float l  = mx + logf(expf(z0 - mx) + expf(z1 - mx));
        out[node] = make_float2(z0 - l, z1 - l);
    }
}

extern "C" void kernel_launch(void* const* d_in, const int* in_sizes, int n_in,
                              void* d_out, int out_size, void* d_ws, size_t ws_size,
                              hipStream_t stream) {
    const float* x  = (const float*)d_in[0];
    const void*  ei = d_in[1];
    const float* W1 = (const float*)d_in[2];
    const float* b1 = (const float*)d_in[3];
    const float* W2 = (const float*)d_in[4];
    const float* b2 = (const float*)d_in[5];
    long long E = (long long)in_sizes[1] / 2;

    char* ws = (char*)d_ws;
    int* flag = (int*)(ws + O_FLAG);
    float2* out = (float2*)d_out;

    int ngrid = (NN + 255) / 256;
    int lgrid = (NN + 15) / 16;
    long long eg = (E + 255) / 256;
    int egrid = (int)(eg > 4096 ? 4096 : eg);

    k_detect<<<1, 64, 0, stream>>>(ei, flag);

    if (ws_size >= SZ_A) {
        float*    dinv  = (float*)(ws + O_DINV);
        float4*   xs    = (float4*)(ws + O_XS);
        float2*   hs2   = (float2*)(ws + O_HS2);
        unsigned* cntX  = (unsigned*)(ws + O_CNTX);
        float*    agg1X = (float*)(ws + O_AG1);
        float*    agg2X = (float*)(ws + O_AG2);

        // zero cntX+agg1X+agg2X (contiguous 19.2 MB)
        k_zero  <<<2048, 256, 0, stream>>>((float4*)(ws + O_CNTX), 1200000);
        k_degA  <<<egrid, 256, 0, stream>>>(ei, E, flag, cntX);
        k_prepA <<<ngrid, 256, 0, stream>>>(x, cntX, dinv, xs);
        k_sc1A  <<<egrid, 256, 0, stream>>>(ei, E, flag, xs, agg1X);
        k_layerA<<<ngrid, 256, 0, stream>>>(W1, b1, W2, dinv, xs, agg1X, hs2);
        k_sc2A  <<<egrid, 256, 0, stream>>>(ei, E, flag, hs2, agg2X);
        k_outA  <<<ngrid, 256, 0, stream>>>(b2, dinv, hs2, agg2X, out);
    } else if (ws_size >= SZ_B) {
        unsigned* cnt   = (unsigned*)(ws + B_CNT);
        unsigned* off   = (unsigned*)(ws + B_OFF);
        unsigned* cur   = (unsigned*)(ws + B_CUR);
        float*    dinv  = (float*)(ws + B_DINV);
        unsigned* csum  = (unsigned*)(ws + B_CSUM);
        unsigned* cbase = (unsigned*)(ws + B_CBASE);
        float4*   xs    = (float4*)(ws + B_XS);
        float2*   hs2   = (float2*)(ws + B_HS2);
        unsigned* ridx  = (unsigned*)(ws + B_RIDX);

        k_zero  <<<98, 256, 0, stream>>>((float4*)(ws + B_CNT), 25000);
        k_histM <<<egrid, 256, 0, stream>>>(ei, E, flag, cnt);
        k_scan1 <<<NCHUNK, 256, 0, stream>>>(cnt, off, csum);
        k_scan2 <<<1, 256, 0, stream>>>(csum, cbase);
        k_scan3 <<<ngrid, 256, 0, stream>>>(cnt, cbase, off, cur, x, dinv, xs);
        k_placeM<<<egrid, 256, 0, stream>>>(ei, E, flag, cur, ridx);
        k_lay1  <<<lgrid, 256, 0, stream>>>(off, cnt, ridx, xs, dinv, W1, b1, W2, hs2);
        k_lay2  <<<lgrid, 256, 0, stream>>>(off, cnt, ridx, hs2, dinv, b2, out);
    }
    // ws < 16.8 MB would be unreachable per R4 evidence (full CSR path ran).
}

// Round 8
// 312.372 us; speedup vs baseline: 3.1876x; 3.1876x over previous
//
#include <hip/hip_runtime.h>
#include <math.h>

#define NN 100000
#define NB 32              // edge slices
#define NRANGE 8           // node ranges
#define RSZ 12500          // NN / NRANGE
#define CHUNK 1024
#define NCHUNK 98          // ceil(NN/1024)

// ---------------- radix ws layout (bytes), total 22802304 ----------------
#define W_FLAG  0
#define W_CNT   256        // u32[NN]
#define W_OFF   400256     // u32[NN]
#define W_DINV  800256     // f32[NN]
#define W_CSUM  1200256    // u32[NCHUNK]
#define W_CBASE 1201280    // u32[NCHUNK]
#define W_XS    1202304    // float4[NN]
#define W_HS2   2802304    // float2[NN]
#define W_B16   3602304    // u16[NB][NN]  6.4 MB
#define W_Z     10002304   // u16 cntP[NB][NN] (P1..P2), then u32 ridx[E] (P3..)
#define SZ_RADIX 22802304
// fallback tier (R4 mid path, 16.8 MB)
#define B_CNT   256
#define B_OFF   400256
#define B_CUR   800256
#define B_DINV  1200256
#define B_CSUM  1600256
#define B_CBASE 1601280
#define B_XS    1602560
#define B_HS2   3202560
#define B_RIDX  4002560
#define SZ_B    16802560

__global__ void k_detect(const void* ei, int* flag) {
    if (blockIdx.x == 0 && threadIdx.x == 0) {
        const long long* p = (const long long*)ei;
        int ok = 1;
        for (int i = 0; i < 64; ++i) {
            long long v = p[i];
            if (v < 0 || v >= NN) { ok = 0; break; }
        }
        *flag = ok;
    }
}

// ---------------- P1: partial histogram per (range, slice), LDS only ----------------
template <typename T>
__device__ __forceinline__ void phist_body(const T* __restrict__ col, long long E,
                                           unsigned short* __restrict__ cntP) {
    __shared__ unsigned lcnt[RSZ];
    int r = blockIdx.x >> 5;           // range
    int b = blockIdx.x & (NB - 1);     // slice
    unsigned lo = (unsigned)r * RSZ;
    for (int i = threadIdx.x; i < RSZ; i += blockDim.x) lcnt[i] = 0u;
    __syncthreads();
    long long S = (E + NB - 1) / NB;
    long long sb = (long long)b * S, se = sb + S < E ? sb + S : E;
    for (long long e = sb + threadIdx.x; e < se; e += blockDim.x) {
        unsigned c = (unsigned)col[e];
        unsigned d = c - lo;
        if (d < RSZ) atomicAdd(&lcnt[d], 1u);
    }
    __syncthreads();
    unsigned short* dst = cntP + (size_t)b * NN + lo;
    for (int i = threadIdx.x; i < RSZ; i += blockDim.x) dst[i] = (unsigned short)lcnt[i];
}
__global__ void k_phist(const void* ei, long long E, const int* flag,
                        unsigned short* cntP) {
    if (*flag) phist_body(((const long long*)ei) + E, E, cntP);
    else       phist_body(((const int*)ei) + E, E, cntP);
}

// ---------------- P2a: reduce partials -> cnt ----------------
__global__ void k_reduce(const unsigned short* __restrict__ cntP, unsigned* __restrict__ cnt) {
    int n = blockIdx.x * blockDim.x + threadIdx.x;
    if (n >= NN) return;
    unsigned s = 0;
#pragma unroll
    for (int b = 0; b < NB; ++b) s += cntP[(size_t)b * NN + n];
    cnt[n] = s;
}

__global__ void k_scan1(const unsigned* __restrict__ cnt, unsigned* __restrict__ off,
                        unsigned* __restrict__ csum) {
    __shared__ unsigned lds[256];
    int t = threadIdx.x;
    int base = blockIdx.x * CHUNK + t * 4;
    unsigned v[4];
#pragma unroll
    for (int k = 0; k < 4; ++k) { int i = base + k; v[k] = (i < NN) ? cnt[i] : 0u; }
    unsigned s = v[0] + v[1] + v[2] + v[3];
    lds[t] = s; __syncthreads();
    for (int o = 1; o < 256; o <<= 1) {
        unsigned add = (t >= o) ? lds[t - o] : 0u; __syncthreads();
        lds[t] += add; __syncthreads();
    }
    unsigned excl = lds[t] - s;
    if (t == 255) csum[blockIdx.x] = lds[255];
#pragma unroll
    for (int k = 0; k < 4; ++k) { int i = base + k; if (i < NN) off[i] = excl; excl += v[k]; }
}
__global__ void k_scan2(unsigned* __restrict__ csum, unsigned* __restrict__ cbase) {
    __shared__ unsigned lds[256];
    int t = threadIdx.x;
    unsigned s = (t < NCHUNK) ? csum[t] : 0u;
    lds[t] = s; __syncthreads();
    for (int o = 1; o < 256; o <<= 1) {
        unsigned add = (t >= o) ? lds[t - o] : 0u; __syncthreads();
        lds[t] += add; __syncthreads();
    }
    if (t < NCHUNK) cbase[t] = lds[t] - s;
}

// ---------------- P2b: finalize off, per-slice bases, dinv, xs ----------------
__global__ void k_final(const unsigned short* __restrict__ cntP,
                        const unsigned* __restrict__ cbase, const unsigned* __restrict__ cnt,
                        unsigned* __restrict__ off, unsigned short* __restrict__ base16,
                        const float* __restrict__ x, float* __restrict__ dinv,
                        float4* __restrict__ xs) {
    int n = blockIdx.x * blockDim.x + threadIdx.x;
    if (n >= NN) return;
    unsigned o = off[n] + cbase[n >> 10];
    off[n] = o;
    unsigned run = 0;
#pragma unroll
    for (int b = 0; b < NB; ++b) {
        base16[(size_t)b * NN + n] = (unsigned short)run;
        run += cntP[(size_t)b * NN + n];
    }
    float d = rsqrtf((float)cnt[n] + 1.0f);     // +1 self-loop
    dinv[n] = d;
    xs[n] = make_float4(x[3*n] * d, x[3*n+1] * d, x[3*n+2] * d, 0.f);
}

// ---------------- P3: place via LDS cursors (no global atomics) ----------------
template <typename T>
__device__ __forceinline__ void pplace_body(const T* __restrict__ ei, long long E,
                                            const unsigned* __restrict__ off,
                                            const unsigned short* __restrict__ base16,
                                            unsigned* __restrict__ ridx) {
    __shared__ unsigned lcur[RSZ];
    int r = blockIdx.x >> 5;
    int b = blockIdx.x & (NB - 1);
    unsigned lo = (unsigned)r * RSZ;
    const unsigned short* bb = base16 + (size_t)b * NN + lo;
    const unsigned* oo = off + lo;
    for (int i = threadIdx.x; i < RSZ; i += blockDim.x) lcur[i] = oo[i] + bb[i];
    __syncthreads();
    long long S = (E + NB - 1) / NB;
    long long sb = (long long)b * S, se = sb + S < E ? sb + S : E;
    for (long long e = sb + threadIdx.x; e < se; e += blockDim.x) {
        unsigned c = (unsigned)ei[E + e];
        unsigned d = c - lo;
        if (d < RSZ) {
            unsigned pos = atomicAdd(&lcur[d], 1u);
            ridx[pos] = (unsigned)ei[e];
        }
    }
}
__global__ void k_pplace(const void* ei, long long E, const int* flag,
                         const unsigned* off, const unsigned short* base16,
                         unsigned* ridx) {
    if (*flag) pplace_body((const long long*)ei, E, off, base16, ridx);
    else       pplace_body((const int*)ei, E, off, base16, ridx);
}

// ---------------- gather layers (R4-proven) ----------------
__global__ void k_lay1(const unsigned* __restrict__ off, const unsigned* __restrict__ cnt,
                       const unsigned* __restrict__ ridx, const float4* __restrict__ xs,
                       const float* __restrict__ dinv,
                       const float* __restrict__ W1, const float* __restrict__ b1,
                       const float* __restrict__ W2, float2* __restrict__ hs2) {
    int lane = threadIdx.x & 15;
    int node = blockIdx.x * (blockDim.x >> 4) + (threadIdx.x >> 4);
    if (node >= NN) return;
    unsigned s = off[node], n = cnt[node];
    float a0 = 0.f, a1 = 0.f, a2 = 0.f;
    for (unsigned k = lane; k < n; k += 16) {
        float4 v = xs[ridx[s + k]];
        a0 += v.x; a1 += v.y; a2 += v.z;
    }
#pragma unroll
    for (int m = 8; m; m >>= 1) {
        a0 += __shfl_xor(a0, m); a1 += __shfl_xor(a1, m); a2 += __shfl_xor(a2, m);
    }
    if (lane == 0) {
        float4 sv = xs[node];
        float d = dinv[node];
        float t0 = d*(a0+sv.x), t1 = d*(a1+sv.y), t2 = d*(a2+sv.z);
        float g0 = 0.f, g1 = 0.f;
#pragma unroll
        for (int j = 0; j < 16; ++j) {
            float h = fmaxf(fmaf(t0, W1[j], fmaf(t1, W1[16+j], fmaf(t2, W1[32+j], b1[j]))), 0.f);
            g0 = fmaf(h, W2[2*j],   g0);
            g1 = fmaf(h, W2[2*j+1], g1);
        }
        hs2[node] = make_float2(g0 * d, g1 * d);
    }
}
__global__ void k_lay2(const unsigned* __restrict__ off, const unsigned* __restrict__ cnt,
                       const unsigned* __restrict__ ridx, const float2* __restrict__ hs2,
                       const float* __restrict__ dinv, const float* __restrict__ b2,
                       float2* __restrict__ out) {
    int lane = threadIdx.x & 15;
    int node = blockIdx.x * (blockDim.x >> 4) + (threadIdx.x >> 4);
    if (node >= NN) return;
    unsigned s = off[node], n = cnt[node];
    float a0 = 0.f, a1 = 0.f;
    for (unsigned k = lane; k < n; k += 16) {
        float2 v = hs2[ridx[s + k]];
        a0 += v.x; a1 += v.y;
    }
#pragma unroll
    for (int m = 8; m; m >>= 1) {
        a0 += __shfl_xor(a0, m); a1 += __shfl_xor(a1, m);
    }
    if (lane == 0) {
        float2 sv = hs2[node];
        float d = dinv[node];
        float z0 = d*(a0+sv.x) + b2[0];
        float z1 = d*(a1+sv.y) + b2[1];
        float mx = fmaxf(z0, z1);
        float l  = mx + logf(expf(z0 - mx) + expf(z1 - mx));
        out[node] = make_float2(z0 - l, z1 - l);
    }
}

// ---------------- fallback tier (R4 mid path: hist + cursor place) ----------------
__global__ void k_zero(float4* z, long long n4) {
    long long stride = (long long)gridDim.x * blockDim.x;
    for (long long i = (long long)blockIdx.x * blockDim.x + threadIdx.x; i < n4; i += stride)
        z[i] = make_float4(0.f, 0.f, 0.f, 0.f);
}
template <typename T>
__device__ __forceinline__ void hist_loop(const T* __restrict__ col, long long E,
                                          unsigned* __restrict__ cnt) {
    long long stride = (long long)gridDim.x * blockDim.x;
    for (long long e = (long long)blockIdx.x * blockDim.x + threadIdx.x; e < E; e += stride)
        atomicAdd(&cnt[(unsigned)col[e]], 1u);
}
__global__ void k_histM(const void* ei, long long E, const int* flag, unsigned* cnt) {
    if (*flag) hist_loop(((const long long*)ei) + E, E, cnt);
    else       hist_loop(((const int*)ei) + E, E, cnt);
}
__global__ void k_scan3(const unsigned* __restrict__ cnt, const unsigned* __restrict__ cbase,
                        unsigned* __restrict__ off, unsigned* __restrict__ cur,
                        const float* __restrict__ x, float* __restrict__ dinv,
                        float4* __restrict__ xs) {
    int i = blockIdx.x * blockDim.x + threadIdx.x;
    if (i >= NN) return;
    unsigned o = off[i] + cbase[i >> 10];
    off[i] = o; cur[i] = o;
    float d = rsqrtf((float)cnt[i] + 1.0f);
    dinv[i] = d;
    xs[i] = make_float4(x[3*i] * d, x[3*i+1] * d, x[3*i+2] * d, 0.f);
}
template <typename T>
__device__ __forceinline__ void placeM_loop(const T* __restrict__ ei, long long E,
                                            unsigned* __restrict__ cur, unsigned* __restrict__ ridx) {
    long long stride = (long long)gridDim.x * blockDim.x;
    for (long long e = (long long)blockIdx.x * blockDim.x + threadIdx.x; e < E; e += stride) {
        unsigned c = (unsigned)ei[E + e];
        unsigned pos = atomicAdd(&cur[c], 1u);
        ridx[pos] = (unsigned)ei[e];
    }
}
__global__ void k_placeM(const void* ei, long long E, const int* flag,
                         unsigned* cur, unsigned* ridx) {
    if (*flag) placeM_loop((const long long*)ei, E, cur, ridx);
    else       placeM_loop((const int*)ei, E, cur, ridx);
}

extern "C" void kernel_launch(void* const* d_in, const int* in_sizes, int n_in,
                              void* d_out, int out_size, void* d_ws, size_t ws_size,
                              hipStream_t stream) {
    const float* x  = (const float*)d_in[0];
    const void*  ei = d_in[1];
    const float* W1 = (const float*)d_in[2];
    const float* b1 = (const float*)d_in[3];
    const float* W2 = (const float*)d_in[4];
    const float* b2 = (const float*)d_in[5];
    long long E = (long long)in_sizes[1] / 2;

    char* ws = (char*)d_ws;
    int* flag = (int*)(ws + W_FLAG);
    float2* out = (float2*)d_out;

    int ngrid = (NN + 255) / 256;      // 391
    int lgrid = (NN + 15) / 16;        // 6250

    k_detect<<<1, 64, 0, stream>>>(ei, flag);

    if (ws_size >= SZ_RADIX) {
        unsigned*       cnt    = (unsigned*)(ws + W_CNT);
        unsigned*       off    = (unsigned*)(ws + W_OFF);
        float*          dinv   = (float*)(ws + W_DINV);
        unsigned*       csum   = (unsigned*)(ws + W_CSUM);
        unsigned*       cbase  = (unsigned*)(ws + W_CBASE);
        float4*         xs     = (float4*)(ws + W_XS);
        float2*         hs2    = (float2*)(ws + W_HS2);
        unsigned short* base16 = (unsigned short*)(ws + W_B16);
        unsigned short* cntP   = (unsigned short*)(ws + W_Z);   // P1..P2b
        unsigned*       ridx   = (unsigned*)(ws + W_Z);         // P3.. (aliases cntP)

        k_phist <<<NRANGE * NB, 512, 0, stream>>>(ei, E, flag, cntP);
        k_reduce<<<ngrid, 256, 0, stream>>>(cntP, cnt);
        k_scan1 <<<NCHUNK, 256, 0, stream>>>(cnt, off, csum);
        k_scan2 <<<1, 256, 0, stream>>>(csum, cbase);
        k_final <<<ngrid, 256, 0, stream>>>(cntP, cbase, cnt, off, base16, x, dinv, xs);
        k_pplace<<<NRANGE * NB, 512, 0, stream>>>(ei, E, flag, off, base16, ridx);
        k_lay1  <<<lgrid, 256, 0, stream>>>(off, cnt, ridx, xs, dinv, W1, b1, W2, hs2);
        k_lay2  <<<lgrid, 256, 0, stream>>>(off, cnt, ridx, hs2, dinv, b2, out);
    } else if (ws_size >= SZ_B) {
        unsigned* cnt   = (unsigned*)(ws + B_CNT);
        unsigned* off   = (unsigned*)(ws + B_OFF);
        unsigned* cur   = (unsigned*)(ws + B_CUR);
        float*    dinv  = (float*)(ws + B_DINV);
        unsigned* csum  = (unsigned*)(ws + B_CSUM);
        unsigned* cbase = (unsigned*)(ws + B_CBASE);
        float4*   xs    = (float4*)(ws + B_XS);
        float2*   hs2   = (float2*)(ws + B_HS2);
        unsigned* ridx  = (unsigned*)(ws + B_RIDX);
        long long eg = (E + 255) / 256;
        int egrid = (int)(eg > 4096 ? 4096 : eg);

        k_zero  <<<98, 256, 0, stream>>>((float4*)(ws + B_CNT), 25000);
        k_histM <<<egrid, 256, 0, stream>>>(ei, E, flag, cnt);
        k_scan1 <<<NCHUNK, 256, 0, stream>>>(cnt, off, csum);
        k_scan2 <<<1, 256, 0, stream>>>(csum, cbase);
        k_scan3 <<<ngrid, 256, 0, stream>>>(cnt, cbase, off, cur, x, dinv, xs);
        k_placeM<<<egrid, 256, 0, stream>>>(ei, E, flag, cur, ridx);
        k_lay1  <<<lgrid, 256, 0, stream>>>(off, cnt, ridx, xs, dinv, W1, b1, W2, hs2);
        k_lay2  <<<lgrid, 256, 0, stream>>>(off, cnt, ridx, hs2, dinv, b2, out);
    }
}

// Round 10
// 219.745 us; speedup vs baseline: 4.5313x; 1.4215x over previous
//
#include <hip/hip_runtime.h>
#include <math.h>

#define NN 100000
#define NB 32              // edge slices
#define NRANGE 8           // node ranges
#define RSZ 12500          // NN / NRANGE
#define CHUNK 1024
#define NCHUNK 98          // ceil(NN/1024)

// ---------------- radix ws layout (bytes), total 22802304 ----------------
#define W_FLAG  0
#define W_CNT   256        // u32[NN]
#define W_OFF   400256     // u32[NN]
#define W_DINV  800256     // f32[NN]
#define W_CSUM  1200256    // u32[NCHUNK]
#define W_CBASE 1201280    // u32[NCHUNK]
#define W_XS    1202304    // float4[NN]
#define W_HS2   2802304    // float2[NN]
#define W_B16   3602304    // u16[NB][NN]  6.4 MB
#define W_Z     10002304   // u16 cntP[NB][NN] (P1..P2), then u32 ridx[E] (P3..)
#define SZ_RADIX 22802304
// fallback tier (R4 mid path, 16.8 MB)
#define B_CNT   256
#define B_OFF   400256
#define B_CUR   800256
#define B_DINV  1200256
#define B_CSUM  1600256
#define B_CBASE 1601280
#define B_XS    1602560
#define B_HS2   3202560
#define B_RIDX  4002560
#define SZ_B    16802560

__global__ void k_detect(const void* ei, int* flag) {
    if (blockIdx.x == 0 && threadIdx.x == 0) {
        const long long* p = (const long long*)ei;
        int ok = 1;
        for (int i = 0; i < 64; ++i) {
            long long v = p[i];
            if (v < 0 || v >= NN) { ok = 0; break; }
        }
        *flag = ok;
    }
}

// ---------------- P1: partial histogram per (range, slice), LDS only ----------------
// 4x-unrolled grid-stride loop: 4 independent, lane-contiguous loads per iter (MLP).
template <typename T>
__device__ __forceinline__ void phist_body(const T* __restrict__ col, long long E,
                                           unsigned* __restrict__ lcnt,
                                           unsigned short* __restrict__ cntP) {
    int r = blockIdx.x >> 5;           // range
    int b = blockIdx.x & (NB - 1);     // slice
    unsigned lo = (unsigned)r * RSZ;
    for (int i = threadIdx.x; i < RSZ; i += blockDim.x) lcnt[i] = 0u;
    __syncthreads();
    long long S = (E + NB - 1) / NB;
    long long sb = (long long)b * S;
    long long se = sb + S < E ? sb + S : E;
    long long B = blockDim.x;
    long long base = sb + threadIdx.x;
    long long nfull = (se - sb) / (4 * B);
    for (long long t = 0; t < nfull; ++t) {
        unsigned c0 = (unsigned)col[base];
        unsigned c1 = (unsigned)col[base + B];
        unsigned c2 = (unsigned)col[base + 2 * B];
        unsigned c3 = (unsigned)col[base + 3 * B];
        unsigned d0 = c0 - lo, d1 = c1 - lo, d2 = c2 - lo, d3 = c3 - lo;
        if (d0 < RSZ) atomicAdd(&lcnt[d0], 1u);
        if (d1 < RSZ) atomicAdd(&lcnt[d1], 1u);
        if (d2 < RSZ) atomicAdd(&lcnt[d2], 1u);
        if (d3 < RSZ) atomicAdd(&lcnt[d3], 1u);
        base += 4 * B;
    }
    for (long long e = base; e < se; e += B) {
        unsigned d = (unsigned)col[e] - lo;
        if (d < RSZ) atomicAdd(&lcnt[d], 1u);
    }
    __syncthreads();
    unsigned short* dst = cntP + (size_t)b * NN + lo;
    for (int i = threadIdx.x; i < RSZ; i += blockDim.x) dst[i] = (unsigned short)lcnt[i];
}
__global__ void k_phist(const void* ei, long long E, const int* flag,
                        unsigned short* cntP) {
    __shared__ unsigned lcnt[RSZ];     // single allocation (hoisted out of template)
    if (*flag) phist_body(((const long long*)ei) + E, E, lcnt, cntP);
    else       phist_body(((const int*)ei) + E, E, lcnt, cntP);
}

// ---------------- P2a: reduce partials -> cnt ----------------
__global__ void k_reduce(const unsigned short* __restrict__ cntP, unsigned* __restrict__ cnt) {
    int n = blockIdx.x * blockDim.x + threadIdx.x;
    if (n >= NN) return;
    unsigned s = 0;
#pragma unroll
    for (int b = 0; b < NB; ++b) s += cntP[(size_t)b * NN + n];
    cnt[n] = s;
}

__global__ void k_scan1(const unsigned* __restrict__ cnt, unsigned* __restrict__ off,
                        unsigned* __restrict__ csum) {
    __shared__ unsigned lds[256];
    int t = threadIdx.x;
    int base = blockIdx.x * CHUNK + t * 4;
    unsigned v[4];
#pragma unroll
    for (int k = 0; k < 4; ++k) { int i = base + k; v[k] = (i < NN) ? cnt[i] : 0u; }
    unsigned s = v[0] + v[1] + v[2] + v[3];
    lds[t] = s; __syncthreads();
    for (int o = 1; o < 256; o <<= 1) {
        unsigned add = (t >= o) ? lds[t - o] : 0u; __syncthreads();
        lds[t] += add; __syncthreads();
    }
    unsigned excl = lds[t] - s;
    if (t == 255) csum[blockIdx.x] = lds[255];
#pragma unroll
    for (int k = 0; k < 4; ++k) { int i = base + k; if (i < NN) off[i] = excl; excl += v[k]; }
}
__global__ void k_scan2(unsigned* __restrict__ csum, unsigned* __restrict__ cbase) {
    __shared__ unsigned lds[256];
    int t = threadIdx.x;
    unsigned s = (t < NCHUNK) ? csum[t] : 0u;
    lds[t] = s; __syncthreads();
    for (int o = 1; o < 256; o <<= 1) {
        unsigned add = (t >= o) ? lds[t - o] : 0u; __syncthreads();
        lds[t] += add; __syncthreads();
    }
    if (t < NCHUNK) cbase[t] = lds[t] - s;
}

// ---------------- P2b: finalize off, per-slice bases, dinv, xs ----------------
__global__ void k_final(const unsigned short* __restrict__ cntP,
                        const unsigned* __restrict__ cbase, const unsigned* __restrict__ cnt,
                        unsigned* __restrict__ off, unsigned short* __restrict__ base16,
                        const float* __restrict__ x, float* __restrict__ dinv,
                        float4* __restrict__ xs) {
    int n = blockIdx.x * blockDim.x + threadIdx.x;
    if (n >= NN) return;
    unsigned o = off[n] + cbase[n >> 10];
    off[n] = o;
    unsigned run = 0;
#pragma unroll
    for (int b = 0; b < NB; ++b) {
        base16[(size_t)b * NN + n] = (unsigned short)run;
        run += cntP[(size_t)b * NN + n];
    }
    float d = rsqrtf((float)cnt[n] + 1.0f);     // +1 self-loop
    dinv[n] = d;
    xs[n] = make_float4(x[3*n] * d, x[3*n+1] * d, x[3*n+2] * d, 0.f);
}

// ---------------- P3: place via LDS cursors (no global atomics) ----------------
template <typename T>
__device__ __forceinline__ void pplace_body(const T* __restrict__ ei, long long E,
                                            const unsigned* __restrict__ off,
                                            const unsigned short* __restrict__ base16,
                                            unsigned* __restrict__ lcur,
                                            unsigned* __restrict__ ridx) {
    int r = blockIdx.x >> 5;
    int b = blockIdx.x & (NB - 1);
    unsigned lo = (unsigned)r * RSZ;
    const unsigned short* bb = base16 + (size_t)b * NN + lo;
    const unsigned* oo = off + lo;
    for (int i = threadIdx.x; i < RSZ; i += blockDim.x) lcur[i] = oo[i] + bb[i];
    __syncthreads();
    const T* col = ei + E;
    long long S = (E + NB - 1) / NB;
    long long sb = (long long)b * S;
    long long se = sb + S < E ? sb + S : E;
    long long B = blockDim.x;
    long long base = sb + threadIdx.x;
    long long nfull = (se - sb) / (4 * B);
    for (long long t = 0; t < nfull; ++t) {
        long long e0 = base, e1 = base + B, e2 = base + 2 * B, e3 = base + 3 * B;
        unsigned d0 = (unsigned)col[e0] - lo;
        unsigned d1 = (unsigned)col[e1] - lo;
        unsigned d2 = (unsigned)col[e2] - lo;
        unsigned d3 = (unsigned)col[e3] - lo;
        if (d0 < RSZ) { unsigned p = atomicAdd(&lcur[d0], 1u); ridx[p] = (unsigned)ei[e0]; }
        if (d1 < RSZ) { unsigned p = atomicAdd(&lcur[d1], 1u); ridx[p] = (unsigned)ei[e1]; }
        if (d2 < RSZ) { unsigned p = atomicAdd(&lcur[d2], 1u); ridx[p] = (unsigned)ei[e2]; }
        if (d3 < RSZ) { unsigned p = atomicAdd(&lcur[d3], 1u); ridx[p] = (unsigned)ei[e3]; }
        base += 4 * B;
    }
    for (long long e = base; e < se; e += B) {
        unsigned d = (unsigned)col[e] - lo;
        if (d < RSZ) { unsigned p = atomicAdd(&lcur[d], 1u); ridx[p] = (unsigned)ei[e]; }
    }
}
__global__ void k_pplace(const void* ei, long long E, const int* flag,
                         const unsigned* off, const unsigned short* base16,
                         unsigned* ridx) {
    __shared__ unsigned lcur[RSZ];     // single allocation (hoisted out of template)
    if (*flag) pplace_body((const long long*)ei, E, off, base16, lcur, ridx);
    else       pplace_body((const int*)ei, E, off, base16, lcur, ridx);
}

// ---------------- gather layers (R4-proven) ----------------
__global__ void k_lay1(const unsigned* __restrict__ off, const unsigned* __restrict__ cnt,
                       const unsigned* __restrict__ ridx, const float4* __restrict__ xs,
                       const float* __restrict__ dinv,
                       const float* __restrict__ W1, const float* __restrict__ b1,
                       const float* __restrict__ W2, float2* __restrict__ hs2) {
    int lane = threadIdx.x & 15;
    int node = blockIdx.x * (blockDim.x >> 4) + (threadIdx.x >> 4);
    if (node >= NN) return;
    unsigned s = off[node], n = cnt[node];
    float a0 = 0.f, a1 = 0.f, a2 = 0.f;
    for (unsigned k = lane; k < n; k += 16) {
        float4 v = xs[ridx[s + k]];
        a0 += v.x; a1 += v.y; a2 += v.z;
    }
#pragma unroll
    for (int m = 8; m; m >>= 1) {
        a0 += __shfl_xor(a0, m); a1 += __shfl_xor(a1, m); a2 += __shfl_xor(a2, m);
    }
    if (lane == 0) {
        float4 sv = xs[node];
        float d = dinv[node];
        float t0 = d*(a0+sv.x), t1 = d*(a1+sv.y), t2 = d*(a2+sv.z);
        float g0 = 0.f, g1 = 0.f;
#pragma unroll
        for (int j = 0; j < 16; ++j) {
            float h = fmaxf(fmaf(t0, W1[j], fmaf(t1, W1[16+j], fmaf(t2, W1[32+j], b1[j]))), 0.f);
            g0 = fmaf(h, W2[2*j],   g0);
            g1 = fmaf(h, W2[2*j+1], g1);
        }
        hs2[node] = make_float2(g0 * d, g1 * d);
    }
}
__global__ void k_lay2(const unsigned* __restrict__ off, const unsigned* __restrict__ cnt,
                       const unsigned* __restrict__ ridx, const float2* __restrict__ hs2,
                       const float* __restrict__ dinv, const float* __restrict__ b2,
                       float2* __restrict__ out) {
    int lane = threadIdx.x & 15;
    int node = blockIdx.x * (blockDim.x >> 4) + (threadIdx.x >> 4);
    if (node >= NN) return;
    unsigned s = off[node], n = cnt[node];
    float a0 = 0.f, a1 = 0.f;
    for (unsigned k = lane; k < n; k += 16) {
        float2 v = hs2[ridx[s + k]];
        a0 += v.x; a1 += v.y;
    }
#pragma unroll
    for (int m = 8; m; m >>= 1) {
        a0 += __shfl_xor(a0, m); a1 += __shfl_xor(a1, m);
    }
    if (lane == 0) {
        float2 sv = hs2[node];
        float d = dinv[node];
        float z0 = d*(a0+sv.x) + b2[0];
        float z1 = d*(a1+sv.y) + b2[1];
        float mx = fmaxf(z0, z1);
        float l  = mx + logf(expf(z0 - mx) + expf(z1 - mx));
        out[node] = make_float2(z0 - l, z1 - l);
    }
}

// ---------------- fallback tier (R4 mid path: hist + cursor place) ----------------
__global__ void k_zero(float4* z, long long n4) {
    long long stride = (long long)gridDim.x * blockDim.x;
    for (long long i = (long long)blockIdx.x * blockDim.x + threadIdx.x; i < n4; i += stride)
        z[i] = make_float4(0.f, 0.f, 0.f, 0.f);
}
template <typename T>
__device__ __forceinline__ void hist_loop(const T* __restrict__ col, long long E,
                                          unsigned* __restrict__ cnt) {
    long long stride = (long long)gridDim.x * blockDim.x;
    for (long long e = (long long)blockIdx.x * blockDim.x + threadIdx.x; e < E; e += stride)
        atomicAdd(&cnt[(unsigned)col[e]], 1u);
}
__global__ void k_histM(const void* ei, long long E, const int* flag, unsigned* cnt) {
    if (*flag) hist_loop(((const long long*)ei) + E, E, cnt);
    else       hist_loop(((const int*)ei) + E, E, cnt);
}
__global__ void k_scan3(const unsigned* __restrict__ cnt, const unsigned* __restrict__ cbase,
                        unsigned* __restrict__ off, unsigned* __restrict__ cur,
                        const float* __restrict__ x, float* __restrict__ dinv,
                        float4* __restrict__ xs) {
    int i = blockIdx.x * blockDim.x + threadIdx.x;
    if (i >= NN) return;
    unsigned o = off[i] + cbase[i >> 10];
    off[i] = o; cur[i] = o;
    float d = rsqrtf((float)cnt[i] + 1.0f);
    dinv[i] = d;
    xs[i] = make_float4(x[3*i] * d, x[3*i+1] * d, x[3*i+2] * d, 0.f);
}
template <typename T>
__device__ __forceinline__ void placeM_loop(const T* __restrict__ ei, long long E,
                                            unsigned* __restrict__ cur, unsigned* __restrict__ ridx) {
    long long stride = (long long)gridDim.x * blockDim.x;
    for (long long e = (long long)blockIdx.x * blockDim.x + threadIdx.x; e < E; e += stride) {
        unsigned c = (unsigned)ei[E + e];
        unsigned pos = atomicAdd(&cur[c], 1u);
        ridx[pos] = (unsigned)ei[e];
    }
}
__global__ void k_placeM(const void* ei, long long E, const int* flag,
                         unsigned* cur, unsigned* ridx) {
    if (*flag) placeM_loop((const long long*)ei, E, cur, ridx);
    else       placeM_loop((const int*)ei, E, cur, ridx);
}

extern "C" void kernel_launch(void* const* d_in, const int* in_sizes, int n_in,
                              void* d_out, int out_size, void* d_ws, size_t ws_size,
                              hipStream_t stream) {
    const float* x  = (const float*)d_in[0];
    const void*  ei = d_in[1];
    const float* W1 = (const float*)d_in[2];
    const float* b1 = (const float*)d_in[3];
    const float* W2 = (const float*)d_in[4];
    const float* b2 = (const float*)d_in[5];
    long long E = (long long)in_sizes[1] / 2;

    char* ws = (char*)d_ws;
    int* flag = (int*)(ws + W_FLAG);
    float2* out = (float2*)d_out;

    int ngrid = (NN + 255) / 256;      // 391
    int lgrid = (NN + 15) / 16;        // 6250

    k_detect<<<1, 64, 0, stream>>>(ei, flag);

    if (ws_size >= SZ_RADIX) {
        unsigned*       cnt    = (unsigned*)(ws + W_CNT);
        unsigned*       off    = (unsigned*)(ws + W_OFF);
        float*          dinv   = (float*)(ws + W_DINV);
        unsigned*       csum   = (unsigned*)(ws + W_CSUM);
        unsigned*       cbase  = (unsigned*)(ws + W_CBASE);
        float4*         xs     = (float4*)(ws + W_XS);
        float2*         hs2    = (float2*)(ws + W_HS2);
        unsigned short* base16 = (unsigned short*)(ws + W_B16);
        unsigned short* cntP   = (unsigned short*)(ws + W_Z);   // P1..P2b
        unsigned*       ridx   = (unsigned*)(ws + W_Z);         // P3.. (aliases cntP)

        k_phist <<<NRANGE * NB, 1024, 0, stream>>>(ei, E, flag, cntP);
        k_reduce<<<ngrid, 256, 0, stream>>>(cntP, cnt);
        k_scan1 <<<NCHUNK, 256, 0, stream>>>(cnt, off, csum);
        k_scan2 <<<1, 256, 0, stream>>>(csum, cbase);
        k_final <<<ngrid, 256, 0, stream>>>(cntP, cbase, cnt, off, base16, x, dinv, xs);
        k_pplace<<<NRANGE * NB, 1024, 0, stream>>>(ei, E, flag, off, base16, ridx);
        k_lay1  <<<lgrid, 256, 0, stream>>>(off, cnt, ridx, xs, dinv, W1, b1, W2, hs2);
        k_lay2  <<<lgrid, 256, 0, stream>>>(off, cnt, ridx, hs2, dinv, b2, out);
    } else if (ws_size >= SZ_B) {
        unsigned* cnt   = (unsigned*)(ws + B_CNT);
        unsigned* off   = (unsigned*)(ws + B_OFF);
        unsigned* cur   = (unsigned*)(ws + B_CUR);
        float*    dinv  = (float*)(ws + B_DINV);
        unsigned* csum  = (unsigned*)(ws + B_CSUM);
        unsigned* cbase = (unsigned*)(ws + B_CBASE);
        float4*   xs    = (float4*)(ws + B_XS);
        float2*   hs2   = (float2*)(ws + B_HS2);
        unsigned* ridx  = (unsigned*)(ws + B_RIDX);
        long long eg = (E + 255) / 256;
        int egrid = (int)(eg > 4096 ? 4096 : eg);

        k_zero  <<<98, 256, 0, stream>>>((float4*)(ws + B_CNT), 25000);
        k_histM <<<egrid, 256, 0, stream>>>(ei, E, flag, cnt);
        k_scan1 <<<NCHUNK, 256, 0, stream>>>(cnt, off, csum);
        k_scan2 <<<1, 256, 0, stream>>>(csum, cbase);
        k_scan3 <<<ngrid, 256, 0, stream>>>(cnt, cbase, off, cur, x, dinv, xs);
        k_placeM<<<egrid, 256, 0, stream>>>(ei, E, flag, cur, ridx);
        k_lay1  <<<lgrid, 256, 0, stream>>>(off, cnt, ridx, xs, dinv, W1, b1, W2, hs2);
        k_lay2  <<<lgrid, 256, 0, stream>>>(off, cnt, ridx, hs2, dinv, b2, out);
    }
}

// Round 11
// 208.668 us; speedup vs baseline: 4.7718x; 1.0531x over previous
//
#include <hip/hip_runtime.h>
#include <math.h>

#define NN 100000
#define NB 32              // edge slices
#define NRANGE 8           // node ranges (== XCD count; r = bid&7 -> XCD-local writes)
#define RSZ 12500          // NN / NRANGE
#define CHUNK 1024
#define NCHUNK 98          // ceil(NN/1024)

// ---------------- radix ws layout (bytes), total 22802304 ----------------
#define W_FLAG  0
#define W_CNT   256        // u32[NN]
#define W_OFF   400256     // u32[NN]
#define W_DINV  800256     // f32[NN]
#define W_CSUM  1200256    // u32[NCHUNK]
#define W_CBASE 1201280    // u32[NCHUNK]
#define W_XS    1202304    // float4[NN]
#define W_HS2   2802304    // float2[NN]
#define W_B16   3602304    // u16[NB][NN]  6.4 MB
#define W_Z     10002304   // u16 cntP[NB][NN] (P1..P2), then u32 ridx[E] (P3..)
#define SZ_RADIX 22802304
// fallback tier (R4 mid path, 16.8 MB)
#define B_CNT   256
#define B_OFF   400256
#define B_CUR   800256
#define B_DINV  1200256
#define B_CSUM  1600256
#define B_CBASE 1601280
#define B_XS    1602560
#define B_HS2   3202560
#define B_RIDX  4002560
#define SZ_B    16802560

__global__ void k_detect(const void* ei, int* flag) {
    if (blockIdx.x == 0 && threadIdx.x == 0) {
        const long long* p = (const long long*)ei;
        int ok = 1;
        for (int i = 0; i < 64; ++i) {
            long long v = p[i];
            if (v < 0 || v >= NN) { ok = 0; break; }
        }
        *flag = ok;
    }
}

// ---------------- P1: partial histogram per (range, slice), LDS only ----------------
// XCD-local decode: range = bid & 7 (matches bid%8 round-robin XCD dispatch).
template <typename T>
__device__ __forceinline__ void phist_body(const T* __restrict__ col, long long E,
                                           unsigned* __restrict__ lcnt,
                                           unsigned short* __restrict__ cntP) {
    int r = blockIdx.x & (NRANGE - 1);     // range -> XCD r
    int b = blockIdx.x >> 3;               // slice
    unsigned lo = (unsigned)r * RSZ;
    for (int i = threadIdx.x; i < RSZ; i += blockDim.x) lcnt[i] = 0u;
    __syncthreads();
    long long S = (E + NB - 1) / NB;
    long long sb = (long long)b * S;
    long long se = sb + S < E ? sb + S : E;
    long long B = blockDim.x;
    long long base = sb + threadIdx.x;
    long long nfull = (se - sb) / (4 * B);
    for (long long t = 0; t < nfull; ++t) {
        unsigned c0 = (unsigned)col[base];
        unsigned c1 = (unsigned)col[base + B];
        unsigned c2 = (unsigned)col[base + 2 * B];
        unsigned c3 = (unsigned)col[base + 3 * B];
        unsigned d0 = c0 - lo, d1 = c1 - lo, d2 = c2 - lo, d3 = c3 - lo;
        if (d0 < RSZ) atomicAdd(&lcnt[d0], 1u);
        if (d1 < RSZ) atomicAdd(&lcnt[d1], 1u);
        if (d2 < RSZ) atomicAdd(&lcnt[d2], 1u);
        if (d3 < RSZ) atomicAdd(&lcnt[d3], 1u);
        base += 4 * B;
    }
    for (long long e = base; e < se; e += B) {
        unsigned d = (unsigned)col[e] - lo;
        if (d < RSZ) atomicAdd(&lcnt[d], 1u);
    }
    __syncthreads();
    unsigned short* dst = cntP + (size_t)b * NN + lo;
    for (int i = threadIdx.x; i < RSZ; i += blockDim.x) dst[i] = (unsigned short)lcnt[i];
}
__global__ void k_phist(const void* ei, long long E, const int* flag,
                        unsigned short* cntP) {
    __shared__ unsigned lcnt[RSZ];
    if (*flag) phist_body(((const long long*)ei) + E, E, lcnt, cntP);
    else       phist_body(((const int*)ei) + E, E, lcnt, cntP);
}

// ---------------- P2a: fused reduce+scan (reads cntP, writes cnt/off/csum) ----------
__global__ void k_scanA(const unsigned short* __restrict__ cntP, unsigned* __restrict__ cnt,
                        unsigned* __restrict__ off, unsigned* __restrict__ csum) {
    __shared__ unsigned lds[256];
    int t = threadIdx.x;
    int base = blockIdx.x * CHUNK + t * 4;
    unsigned v[4] = {0u, 0u, 0u, 0u};
    if (base + 3 < NN) {
#pragma unroll
        for (int b = 0; b < NB; ++b) {
            const unsigned short* p = cntP + (size_t)b * NN + base;
            v[0] += p[0]; v[1] += p[1]; v[2] += p[2]; v[3] += p[3];
        }
    } else {
#pragma unroll
        for (int k = 0; k < 4; ++k) {
            int i = base + k;
            if (i < NN) { unsigned s = 0; for (int b = 0; b < NB; ++b) s += cntP[(size_t)b * NN + i]; v[k] = s; }
        }
    }
#pragma unroll
    for (int k = 0; k < 4; ++k) { int i = base + k; if (i < NN) cnt[i] = v[k]; }
    unsigned s = v[0] + v[1] + v[2] + v[3];
    lds[t] = s; __syncthreads();
    for (int o = 1; o < 256; o <<= 1) {
        unsigned add = (t >= o) ? lds[t - o] : 0u; __syncthreads();
        lds[t] += add; __syncthreads();
    }
    unsigned excl = lds[t] - s;
    if (t == 255) csum[blockIdx.x] = lds[255];
#pragma unroll
    for (int k = 0; k < 4; ++k) { int i = base + k; if (i < NN) off[i] = excl; excl += v[k]; }
}

__global__ void k_scan1(const unsigned* __restrict__ cnt, unsigned* __restrict__ off,
                        unsigned* __restrict__ csum) {
    __shared__ unsigned lds[256];
    int t = threadIdx.x;
    int base = blockIdx.x * CHUNK + t * 4;
    unsigned v[4];
#pragma unroll
    for (int k = 0; k < 4; ++k) { int i = base + k; v[k] = (i < NN) ? cnt[i] : 0u; }
    unsigned s = v[0] + v[1] + v[2] + v[3];
    lds[t] = s; __syncthreads();
    for (int o = 1; o < 256; o <<= 1) {
        unsigned add = (t >= o) ? lds[t - o] : 0u; __syncthreads();
        lds[t] += add; __syncthreads();
    }
    unsigned excl = lds[t] - s;
    if (t == 255) csum[blockIdx.x] = lds[255];
#pragma unroll
    for (int k = 0; k < 4; ++k) { int i = base + k; if (i < NN) off[i] = excl; excl += v[k]; }
}
__global__ void k_scan2(unsigned* __restrict__ csum, unsigned* __restrict__ cbase) {
    __shared__ unsigned lds[256];
    int t = threadIdx.x;
    unsigned s = (t < NCHUNK) ? csum[t] : 0u;
    lds[t] = s; __syncthreads();
    for (int o = 1; o < 256; o <<= 1) {
        unsigned add = (t >= o) ? lds[t - o] : 0u; __syncthreads();
        lds[t] += add; __syncthreads();
    }
    if (t < NCHUNK) cbase[t] = lds[t] - s;
}

// ---------------- P2b: finalize off, per-slice bases, dinv, xs ----------------
__global__ void k_final(const unsigned short* __restrict__ cntP,
                        const unsigned* __restrict__ cbase, const unsigned* __restrict__ cnt,
                        unsigned* __restrict__ off, unsigned short* __restrict__ base16,
                        const float* __restrict__ x, float* __restrict__ dinv,
                        float4* __restrict__ xs) {
    int n = blockIdx.x * blockDim.x + threadIdx.x;
    if (n >= NN) return;
    unsigned o = off[n] + cbase[n >> 10];
    off[n] = o;
    unsigned run = 0;
#pragma unroll
    for (int b = 0; b < NB; ++b) {
        base16[(size_t)b * NN + n] = (unsigned short)run;
        run += cntP[(size_t)b * NN + n];
    }
    float d = rsqrtf((float)cnt[n] + 1.0f);     // +1 self-loop
    dinv[n] = d;
    xs[n] = make_float4(x[3*n] * d, x[3*n+1] * d, x[3*n+2] * d, 0.f);
}

// ---------------- P3: place via LDS cursors; XCD-local range decode ----------------
template <typename T>
__device__ __forceinline__ void pplace_body(const T* __restrict__ ei, long long E,
                                            const unsigned* __restrict__ off,
                                            const unsigned short* __restrict__ base16,
                                            unsigned* __restrict__ lcur,
                                            unsigned* __restrict__ ridx) {
    int r = blockIdx.x & (NRANGE - 1);     // range -> XCD r: all writers of range r share one L2
    int b = blockIdx.x >> 3;               // slice
    unsigned lo = (unsigned)r * RSZ;
    const unsigned short* bb = base16 + (size_t)b * NN + lo;
    const unsigned* oo = off + lo;
    for (int i = threadIdx.x; i < RSZ; i += blockDim.x) lcur[i] = oo[i] + bb[i];
    __syncthreads();
    const T* col = ei + E;
    long long S = (E + NB - 1) / NB;
    long long sb = (long long)b * S;
    long long se = sb + S < E ? sb + S : E;
    long long B = blockDim.x;
    long long base = sb + threadIdx.x;
    long long nfull = (se - sb) / (4 * B);
    for (long long t = 0; t < nfull; ++t) {
        long long e0 = base, e1 = base + B, e2 = base + 2 * B, e3 = base + 3 * B;
        unsigned d0 = (unsigned)col[e0] - lo;
        unsigned d1 = (unsigned)col[e1] - lo;
        unsigned d2 = (unsigned)col[e2] - lo;
        unsigned d3 = (unsigned)col[e3] - lo;
        if (d0 < RSZ) { unsigned p = atomicAdd(&lcur[d0], 1u); ridx[p] = (unsigned)ei[e0]; }
        if (d1 < RSZ) { unsigned p = atomicAdd(&lcur[d1], 1u); ridx[p] = (unsigned)ei[e1]; }
        if (d2 < RSZ) { unsigned p = atomicAdd(&lcur[d2], 1u); ridx[p] = (unsigned)ei[e2]; }
        if (d3 < RSZ) { unsigned p = atomicAdd(&lcur[d3], 1u); ridx[p] = (unsigned)ei[e3]; }
        base += 4 * B;
    }
    for (long long e = base; e < se; e += B) {
        unsigned d = (unsigned)col[e] - lo;
        if (d < RSZ) { unsigned p = atomicAdd(&lcur[d], 1u); ridx[p] = (unsigned)ei[e]; }
    }
}
__global__ void k_pplace(const void* ei, long long E, const int* flag,
                         const unsigned* off, const unsigned short* base16,
                         unsigned* ridx) {
    __shared__ unsigned lcur[RSZ];
    if (*flag) pplace_body((const long long*)ei, E, off, base16, lcur, ridx);
    else       pplace_body((const int*)ei, E, off, base16, lcur, ridx);
}

// ---------------- gather layers (R4-proven) ----------------
__global__ void k_lay1(const unsigned* __restrict__ off, const unsigned* __restrict__ cnt,
                       const unsigned* __restrict__ ridx, const float4* __restrict__ xs,
                       const float* __restrict__ dinv,
                       const float* __restrict__ W1, const float* __restrict__ b1,
                       const float* __restrict__ W2, float2* __restrict__ hs2) {
    int lane = threadIdx.x & 15;
    int node = blockIdx.x * (blockDim.x >> 4) + (threadIdx.x >> 4);
    if (node >= NN) return;
    unsigned s = off[node], n = cnt[node];
    float a0 = 0.f, a1 = 0.f, a2 = 0.f;
    for (unsigned k = lane; k < n; k += 16) {
        float4 v = xs[ridx[s + k]];
        a0 += v.x; a1 += v.y; a2 += v.z;
    }
#pragma unroll
    for (int m = 8; m; m >>= 1) {
        a0 += __shfl_xor(a0, m); a1 += __shfl_xor(a1, m); a2 += __shfl_xor(a2, m);
    }
    if (lane == 0) {
        float4 sv = xs[node];
        float d = dinv[node];
        float t0 = d*(a0+sv.x), t1 = d*(a1+sv.y), t2 = d*(a2+sv.z);
        float g0 = 0.f, g1 = 0.f;
#pragma unroll
        for (int j = 0; j < 16; ++j) {
            float h = fmaxf(fmaf(t0, W1[j], fmaf(t1, W1[16+j], fmaf(t2, W1[32+j], b1[j]))), 0.f);
            g0 = fmaf(h, W2[2*j],   g0);
            g1 = fmaf(h, W2[2*j+1], g1);
        }
        hs2[node] = make_float2(g0 * d, g1 * d);
    }
}
__global__ void k_lay2(const unsigned* __restrict__ off, const unsigned* __restrict__ cnt,
                       const unsigned* __restrict__ ridx, const float2* __restrict__ hs2,
                       const float* __restrict__ dinv, const float* __restrict__ b2,
                       float2* __restrict__ out) {
    int lane = threadIdx.x & 15;
    int node = blockIdx.x * (blockDim.x >> 4) + (threadIdx.x >> 4);
    if (node >= NN) return;
    unsigned s = off[node], n = cnt[node];
    float a0 = 0.f, a1 = 0.f;
    for (unsigned k = lane; k < n; k += 16) {
        float2 v = hs2[ridx[s + k]];
        a0 += v.x; a1 += v.y;
    }
#pragma unroll
    for (int m = 8; m; m >>= 1) {
        a0 += __shfl_xor(a0, m); a1 += __shfl_xor(a1, m);
    }
    if (lane == 0) {
        float2 sv = hs2[node];
        float d = dinv[node];
        float z0 = d*(a0+sv.x) + b2[0];
        float z1 = d*(a1+sv.y) + b2[1];
        float mx = fmaxf(z0, z1);
        float l  = mx + logf(expf(z0 - mx) + expf(z1 - mx));
        out[node] = make_float2(z0 - l, z1 - l);
    }
}

// ---------------- fallback tier (R4 mid path: hist + cursor place) ----------------
__global__ void k_zero(float4* z, long long n4) {
    long long stride = (long long)gridDim.x * blockDim.x;
    for (long long i = (long long)blockIdx.x * blockDim.x + threadIdx.x; i < n4; i += stride)
        z[i] = make_float4(0.f, 0.f, 0.f, 0.f);
}
template <typename T>
__device__ __forceinline__ void hist_loop(const T* __restrict__ col, long long E,
                                          unsigned* __restrict__ cnt) {
    long long stride = (long long)gridDim.x * blockDim.x;
    for (long long e = (long long)blockIdx.x * blockDim.x + threadIdx.x; e < E; e += stride)
        atomicAdd(&cnt[(unsigned)col[e]], 1u);
}
__global__ void k_histM(const void* ei, long long E, const int* flag, unsigned* cnt) {
    if (*flag) hist_loop(((const long long*)ei) + E, E, cnt);
    else       hist_loop(((const int*)ei) + E, E, cnt);
}
__global__ void k_scan3(const unsigned* __restrict__ cnt, const unsigned* __restrict__ cbase,
                        unsigned* __restrict__ off, unsigned* __restrict__ cur,
                        const float* __restrict__ x, float* __restrict__ dinv,
                        float4* __restrict__ xs) {
    int i = blockIdx.x * blockDim.x + threadIdx.x;
    if (i >= NN) return;
    unsigned o = off[i] + cbase[i >> 10];
    off[i] = o; cur[i] = o;
    float d = rsqrtf((float)cnt[i] + 1.0f);
    dinv[i] = d;
    xs[i] = make_float4(x[3*i] * d, x[3*i+1] * d, x[3*i+2] * d, 0.f);
}
template <typename T>
__device__ __forceinline__ void placeM_loop(const T* __restrict__ ei, long long E,
                                            unsigned* __restrict__ cur, unsigned* __restrict__ ridx) {
    long long stride = (long long)gridDim.x * blockDim.x;
    for (long long e = (long long)blockIdx.x * blockDim.x + threadIdx.x; e < E; e += stride) {
        unsigned c = (unsigned)ei[E + e];
        unsigned pos = atomicAdd(&cur[c], 1u);
        ridx[pos] = (unsigned)ei[e];
    }
}
__global__ void k_placeM(const void* ei, long long E, const int* flag,
                         unsigned* cur, unsigned* ridx) {
    if (*flag) placeM_loop((const long long*)ei, E, cur, ridx);
    else       placeM_loop((const int*)ei, E, cur, ridx);
}

extern "C" void kernel_launch(void* const* d_in, const int* in_sizes, int n_in,
                              void* d_out, int out_size, void* d_ws, size_t ws_size,
                              hipStream_t stream) {
    const float* x  = (const float*)d_in[0];
    const void*  ei = d_in[1];
    const float* W1 = (const float*)d_in[2];
    const float* b1 = (const float*)d_in[3];
    const float* W2 = (const float*)d_in[4];
    const float* b2 = (const float*)d_in[5];
    long long E = (long long)in_sizes[1] / 2;

    char* ws = (char*)d_ws;
    int* flag = (int*)(ws + W_FLAG);
    float2* out = (float2*)d_out;

    int ngrid = (NN + 255) / 256;      // 391
    int lgrid = (NN + 15) / 16;        // 6250

    k_detect<<<1, 64, 0, stream>>>(ei, flag);

    if (ws_size >= SZ_RADIX) {
        unsigned*       cnt    = (unsigned*)(ws + W_CNT);
        unsigned*       off    = (unsigned*)(ws + W_OFF);
        float*          dinv   = (float*)(ws + W_DINV);
        unsigned*       csum   = (unsigned*)(ws + W_CSUM);
        unsigned*       cbase  = (unsigned*)(ws + W_CBASE);
        float4*         xs     = (float4*)(ws + W_XS);
        float2*         hs2    = (float2*)(ws + W_HS2);
        unsigned short* base16 = (unsigned short*)(ws + W_B16);
        unsigned short* cntP   = (unsigned short*)(ws + W_Z);   // P1..P2b
        unsigned*       ridx   = (unsigned*)(ws + W_Z);         // P3.. (aliases cntP)

        k_phist <<<NRANGE * NB, 1024, 0, stream>>>(ei, E, flag, cntP);
        k_scanA <<<NCHUNK, 256, 0, stream>>>(cntP, cnt, off, csum);
        k_scan2 <<<1, 256, 0, stream>>>(csum, cbase);
        k_final <<<ngrid, 256, 0, stream>>>(cntP, cbase, cnt, off, base16, x, dinv, xs);
        k_pplace<<<NRANGE * NB, 1024, 0, stream>>>(ei, E, flag, off, base16, ridx);
        k_lay1  <<<lgrid, 256, 0, stream>>>(off, cnt, ridx, xs, dinv, W1, b1, W2, hs2);
        k_lay2  <<<lgrid, 256, 0, stream>>>(off, cnt, ridx, hs2, dinv, b2, out);
    } else if (ws_size >= SZ_B) {
        unsigned* cnt   = (unsigned*)(ws + B_CNT);
        unsigned* off   = (unsigned*)(ws + B_OFF);
        unsigned* cur   = (unsigned*)(ws + B_CUR);
        float*    dinv  = (float*)(ws + B_DINV);
        unsigned* csum  = (unsigned*)(ws + B_CSUM);
        unsigned* cbase = (unsigned*)(ws + B_CBASE);
        float4*   xs    = (float4*)(ws + B_XS);
        float2*   hs2   = (float2*)(ws + B_HS2);
        unsigned* ridx  = (unsigned*)(ws + B_RIDX);
        long long eg = (E + 255) / 256;
        int egrid = (int)(eg > 4096 ? 4096 : eg);

        k_zero  <<<98, 256, 0, stream>>>((float4*)(ws + B_CNT), 25000);
        k_histM <<<egrid, 256, 0, stream>>>(ei, E, flag, cnt);
        k_scan1 <<<NCHUNK, 256, 0, stream>>>(cnt, off, csum);
        k_scan2 <<<1, 256, 0, stream>>>(csum, cbase);
        k_scan3 <<<ngrid, 256, 0, stream>>>(cnt, cbase, off, cur, x, dinv, xs);
        k_placeM<<<egrid, 256, 0, stream>>>(ei, E, flag, cur, ridx);
        k_lay1  <<<lgrid, 256, 0, stream>>>(off, cnt, ridx, xs, dinv, W1, b1, W2, hs2);
        k_lay2  <<<lgrid, 256, 0, stream>>>(off, cnt, ridx, hs2, dinv, b2, out);
    }
}

// Round 12
// 176.392 us; speedup vs baseline: 5.6450x; 1.1830x over previous
//
#include <hip/hip_runtime.h>
#include <math.h>

#define NN 100000
#define NB 32              // sub-chunks per range (hist/place)
#define NRANGE 8           // node ranges (== XCDs; r = bid&7)
#define RSZ 12500          // NN / NRANGE
#define NS 256             // staging slices
#define CHUNK 1024
#define NCHUNK 98          // ceil(NN/1024)

// ---------------- S tier (staged partition), total 35618048 ----------------
#define S_FLAG  0
#define S_BCNT  256        // u32[NS*8]
#define S_BOFF  8448       // u32[NS*8]
#define S_ROFF  16640      // u32[9]
#define S_CNT   16896      // u32[NN]
#define S_OFF   416896     // u32[NN]
#define S_DINV  816896     // f32[NN]
#define S_CSUM  1216896    // u32[NCHUNK]
#define S_CBASE 1217536    // u32[NCHUNK]
#define S_XS    1218048    // float4[NN]
#define S_HS2   2818048    // float2[NN]
#define S_B16   3618048    // u16[NB][NN] 6.4MB
#define S_STG   10018048   // u32[E] 12.8MB packed (row<<14 | colLocal)
#define S_CNTP  22818048   // u16[NB][NN] (dead after k_final)
#define S_RIDX  22818048   // u32[E] (aliases cntP region)
#define SZ_S    35618048
// ---------------- radix tier (R11 design), total 22802304 ----------------
#define W_FLAG  0
#define W_CNT   256
#define W_OFF   400256
#define W_DINV  800256
#define W_CSUM  1200256
#define W_CBASE 1201280
#define W_XS    1202304
#define W_HS2   2802304
#define W_B16   3602304
#define W_Z     10002304
#define SZ_RADIX 22802304
// ---------------- B tier (R4 mid path), 16.8MB ----------------
#define B_CNT   256
#define B_OFF   400256
#define B_CUR   800256
#define B_DINV  1200256
#define B_CSUM  1600256
#define B_CBASE 1601280
#define B_XS    1602560
#define B_HS2   3202560
#define B_RIDX  4002560
#define SZ_B    16802560

__global__ void k_detect(const void* ei, int* flag) {
    if (blockIdx.x == 0 && threadIdx.x == 0) {
        const long long* p = (const long long*)ei;
        int ok = 1;
        for (int i = 0; i < 64; ++i) {
            long long v = p[i];
            if (v < 0 || v >= NN) { ok = 0; break; }
        }
        *flag = ok;
    }
}

// =================== S tier ===================
// A1: per-slice per-range counts. lds8[8][64] avoids same-address contention.
template <typename T>
__device__ __forceinline__ void bcount_body(const T* __restrict__ col, long long E,
                                            unsigned* __restrict__ lds8,
                                            unsigned* __restrict__ bucketCnt) {
    int s = blockIdx.x;
    for (int i = threadIdx.x; i < 8 * 64; i += blockDim.x) lds8[i] = 0u;
    __syncthreads();
    long long S = (E + NS - 1) / NS;
    long long sb = (long long)s * S, se = sb + S < E ? sb + S : E;
    long long B = blockDim.x;
    long long base = sb + threadIdx.x;
    int lane = threadIdx.x & 63;
    long long nfull = (se - sb) / (4 * B);
    for (long long t = 0; t < nfull; ++t) {
        unsigned c0 = (unsigned)col[base];
        unsigned c1 = (unsigned)col[base + B];
        unsigned c2 = (unsigned)col[base + 2 * B];
        unsigned c3 = (unsigned)col[base + 3 * B];
        atomicAdd(&lds8[(c0 / RSZ) * 64 + lane], 1u);
        atomicAdd(&lds8[(c1 / RSZ) * 64 + lane], 1u);
        atomicAdd(&lds8[(c2 / RSZ) * 64 + lane], 1u);
        atomicAdd(&lds8[(c3 / RSZ) * 64 + lane], 1u);
        base += 4 * B;
    }
    for (long long e = base; e < se; e += B)
        atomicAdd(&lds8[((unsigned)col[e] / RSZ) * 64 + lane], 1u);
    __syncthreads();
    if (threadIdx.x < 8) {
        unsigned t = 0;
        for (int j = 0; j < 64; ++j) t += lds8[threadIdx.x * 64 + j];
        bucketCnt[s * 8 + threadIdx.x] = t;
    }
}
__global__ void k_bcount(const void* ei, long long E, const int* flag,
                         unsigned* bucketCnt) {
    __shared__ unsigned lds8[8 * 64];
    if (*flag) bcount_body(((const long long*)ei) + E, E, lds8, bucketCnt);
    else       bcount_body(((const int*)ei) + E, E, lds8, bucketCnt);
}

// range-major scan of 2048 buckets (j = g*NS + s); emits bucketOff + rangeOff[9]
__global__ void k_bscan(const unsigned* __restrict__ bucketCnt,
                        unsigned* __restrict__ bucketOff, unsigned* __restrict__ rangeOff) {
    __shared__ unsigned lds[1024];
    int t = threadIdx.x;
    int j0 = 2 * t, j1 = 2 * t + 1;
    unsigned v0 = bucketCnt[(j0 & (NS - 1)) * 8 + (j0 >> 8)];
    unsigned v1 = bucketCnt[(j1 & (NS - 1)) * 8 + (j1 >> 8)];
    unsigned s = v0 + v1;
    lds[t] = s; __syncthreads();
    for (int o = 1; o < 1024; o <<= 1) {
        unsigned add = (t >= o) ? lds[t - o] : 0u; __syncthreads();
        lds[t] += add; __syncthreads();
    }
    unsigned excl = lds[t] - s;
    bucketOff[j0] = excl;
    bucketOff[j1] = excl + v0;
    if ((j0 & (NS - 1)) == 0) rangeOff[j0 >> 8] = excl;
    if (t == 1023) rangeOff[8] = lds[1023];
}

// A2: stage packed edges at bucket offsets (8 LDS cursors per block)
template <typename T>
__device__ __forceinline__ void stage_body(const T* __restrict__ ei, long long E,
                                           const unsigned* __restrict__ bucketOff,
                                           unsigned* __restrict__ lcur,
                                           unsigned* __restrict__ staged) {
    int s = blockIdx.x;
    if (threadIdx.x < 8) lcur[threadIdx.x] = bucketOff[threadIdx.x * NS + s];
    __syncthreads();
    const T* col = ei + E;
    long long S = (E + NS - 1) / NS;
    long long sb = (long long)s * S, se = sb + S < E ? sb + S : E;
    long long B = blockDim.x;
    long long base = sb + threadIdx.x;
    long long nfull = (se - sb) / (4 * B);
    for (long long t = 0; t < nfull; ++t) {
        long long e0 = base, e1 = base + B, e2 = base + 2 * B, e3 = base + 3 * B;
        unsigned c0 = (unsigned)col[e0], c1 = (unsigned)col[e1];
        unsigned c2 = (unsigned)col[e2], c3 = (unsigned)col[e3];
        unsigned r0 = (unsigned)ei[e0], r1 = (unsigned)ei[e1];
        unsigned r2 = (unsigned)ei[e2], r3 = (unsigned)ei[e3];
        unsigned g0 = c0 / RSZ, g1 = c1 / RSZ, g2 = c2 / RSZ, g3 = c3 / RSZ;
        unsigned p0 = atomicAdd(&lcur[g0], 1u);
        unsigned p1 = atomicAdd(&lcur[g1], 1u);
        unsigned p2 = atomicAdd(&lcur[g2], 1u);
        unsigned p3 = atomicAdd(&lcur[g3], 1u);
        staged[p0] = (r0 << 14) | (c0 - g0 * RSZ);
        staged[p1] = (r1 << 14) | (c1 - g1 * RSZ);
        staged[p2] = (r2 << 14) | (c2 - g2 * RSZ);
        staged[p3] = (r3 << 14) | (c3 - g3 * RSZ);
        base += 4 * B;
    }
    for (long long e = base; e < se; e += B) {
        unsigned c = (unsigned)col[e], r = (unsigned)ei[e];
        unsigned g = c / RSZ;
        unsigned p = atomicAdd(&lcur[g], 1u);
        staged[p] = (r << 14) | (c - g * RSZ);
    }
}
__global__ void k_stage(const void* ei, long long E, const int* flag,
                        const unsigned* bucketOff, unsigned* staged) {
    __shared__ unsigned lcur[8];
    if (*flag) stage_body((const long long*)ei, E, bucketOff, lcur, staged);
    else       stage_body((const int*)ei, E, bucketOff, lcur, staged);
}

// B: per-node hist from staged (contiguous reads, XCD-local)
__global__ void k_shist(const unsigned* __restrict__ staged, const unsigned* __restrict__ rangeOff,
                        unsigned short* __restrict__ cntP) {
    __shared__ unsigned lcnt[RSZ];
    int r = blockIdx.x & (NRANGE - 1);
    int s = blockIdx.x >> 3;
    for (int i = threadIdx.x; i < RSZ; i += blockDim.x) lcnt[i] = 0u;
    __syncthreads();
    unsigned A = rangeOff[r], Bnd = rangeOff[r + 1];
    unsigned L = (Bnd - A + NB - 1) / NB;
    unsigned cb = A + s * L;
    unsigned ce = cb + L < Bnd ? cb + L : Bnd;
    for (unsigned i = cb + threadIdx.x; i < ce; i += blockDim.x)
        atomicAdd(&lcnt[staged[i] & 16383u], 1u);
    __syncthreads();
    unsigned short* dst = cntP + (size_t)s * NN + (unsigned)r * RSZ;
    for (int i = threadIdx.x; i < RSZ; i += blockDim.x) dst[i] = (unsigned short)lcnt[i];
}

// C: place from staged via LDS cursors (reads+writes L2-local)
__global__ void k_splace(const unsigned* __restrict__ staged, const unsigned* __restrict__ rangeOff,
                         const unsigned* __restrict__ off, const unsigned short* __restrict__ base16,
                         unsigned* __restrict__ ridx) {
    __shared__ unsigned lcur[RSZ];
    int r = blockIdx.x & (NRANGE - 1);
    int s = blockIdx.x >> 3;
    unsigned lo = (unsigned)r * RSZ;
    const unsigned short* bb = base16 + (size_t)s * NN + lo;
    const unsigned* oo = off + lo;
    for (int i = threadIdx.x; i < RSZ; i += blockDim.x) lcur[i] = oo[i] + bb[i];
    __syncthreads();
    unsigned A = rangeOff[r], Bnd = rangeOff[r + 1];
    unsigned L = (Bnd - A + NB - 1) / NB;
    unsigned cb = A + s * L;
    unsigned ce = cb + L < Bnd ? cb + L : Bnd;
    for (unsigned i = cb + threadIdx.x; i < ce; i += blockDim.x) {
        unsigned p = staged[i];
        unsigned pos = atomicAdd(&lcur[p & 16383u], 1u);
        ridx[pos] = p >> 14;
    }
}

// =================== shared: scans / final / layers ===================
__global__ void k_scanA(const unsigned short* __restrict__ cntP, unsigned* __restrict__ cnt,
                        unsigned* __restrict__ off, unsigned* __restrict__ csum) {
    __shared__ unsigned lds[256];
    int t = threadIdx.x;
    int base = blockIdx.x * CHUNK + t * 4;
    unsigned v[4] = {0u, 0u, 0u, 0u};
    if (base + 3 < NN) {
#pragma unroll
        for (int b = 0; b < NB; ++b) {
            const unsigned short* p = cntP + (size_t)b * NN + base;
            v[0] += p[0]; v[1] += p[1]; v[2] += p[2]; v[3] += p[3];
        }
    } else {
#pragma unroll
        for (int k = 0; k < 4; ++k) {
            int i = base + k;
            if (i < NN) { unsigned s = 0; for (int b = 0; b < NB; ++b) s += cntP[(size_t)b * NN + i]; v[k] = s; }
        }
    }
#pragma unroll
    for (int k = 0; k < 4; ++k) { int i = base + k; if (i < NN) cnt[i] = v[k]; }
    unsigned s = v[0] + v[1] + v[2] + v[3];
    lds[t] = s; __syncthreads();
    for (int o = 1; o < 256; o <<= 1) {
        unsigned add = (t >= o) ? lds[t - o] : 0u; __syncthreads();
        lds[t] += add; __syncthreads();
    }
    unsigned excl = lds[t] - s;
    if (t == 255) csum[blockIdx.x] = lds[255];
#pragma unroll
    for (int k = 0; k < 4; ++k) { int i = base + k; if (i < NN) off[i] = excl; excl += v[k]; }
}
__global__ void k_scan1(const unsigned* __restrict__ cnt, unsigned* __restrict__ off,
                        unsigned* __restrict__ csum) {
    __shared__ unsigned lds[256];
    int t = threadIdx.x;
    int base = blockIdx.x * CHUNK + t * 4;
    unsigned v[4];
#pragma unroll
    for (int k = 0; k < 4; ++k) { int i = base + k; v[k] = (i < NN) ? cnt[i] : 0u; }
    unsigned s = v[0] + v[1] + v[2] + v[3];
    lds[t] = s; __syncthreads();
    for (int o = 1; o < 256; o <<= 1) {
        unsigned add = (t >= o) ? lds[t - o] : 0u; __syncthreads();
        lds[t] += add; __syncthreads();
    }
    unsigned excl = lds[t] - s;
    if (t == 255) csum[blockIdx.x] = lds[255];
#pragma unroll
    for (int k = 0; k < 4; ++k) { int i = base + k; if (i < NN) off[i] = excl; excl += v[k]; }
}
__global__ void k_scan2(unsigned* __restrict__ csum, unsigned* __restrict__ cbase) {
    __shared__ unsigned lds[256];
    int t = threadIdx.x;
    unsigned s = (t < NCHUNK) ? csum[t] : 0u;
    lds[t] = s; __syncthreads();
    for (int o = 1; o < 256; o <<= 1) {
        unsigned add = (t >= o) ? lds[t - o] : 0u; __syncthreads();
        lds[t] += add; __syncthreads();
    }
    if (t < NCHUNK) cbase[t] = lds[t] - s;
}
__global__ void k_final(const unsigned short* __restrict__ cntP,
                        const unsigned* __restrict__ cbase, const unsigned* __restrict__ cnt,
                        unsigned* __restrict__ off, unsigned short* __restrict__ base16,
                        const float* __restrict__ x, float* __restrict__ dinv,
                        float4* __restrict__ xs) {
    int n = blockIdx.x * blockDim.x + threadIdx.x;
    if (n >= NN) return;
    unsigned o = off[n] + cbase[n >> 10];
    off[n] = o;
    unsigned run = 0;
#pragma unroll
    for (int b = 0; b < NB; ++b) {
        base16[(size_t)b * NN + n] = (unsigned short)run;
        run += cntP[(size_t)b * NN + n];
    }
    float d = rsqrtf((float)cnt[n] + 1.0f);
    dinv[n] = d;
    xs[n] = make_float4(x[3*n] * d, x[3*n+1] * d, x[3*n+2] * d, 0.f);
}
__global__ void k_lay1(const unsigned* __restrict__ off, const unsigned* __restrict__ cnt,
                       const unsigned* __restrict__ ridx, const float4* __restrict__ xs,
                       const float* __restrict__ dinv,
                       const float* __restrict__ W1, const float* __restrict__ b1,
                       const float* __restrict__ W2, float2* __restrict__ hs2) {
    int lane = threadIdx.x & 15;
    int node = blockIdx.x * (blockDim.x >> 4) + (threadIdx.x >> 4);
    if (node >= NN) return;
    unsigned s = off[node], n = cnt[node];
    float a0 = 0.f, a1 = 0.f, a2 = 0.f;
    for (unsigned k = lane; k < n; k += 16) {
        float4 v = xs[ridx[s + k]];
        a0 += v.x; a1 += v.y; a2 += v.z;
    }
#pragma unroll
    for (int m = 8; m; m >>= 1) {
        a0 += __shfl_xor(a0, m); a1 += __shfl_xor(a1, m); a2 += __shfl_xor(a2, m);
    }
    if (lane == 0) {
        float4 sv = xs[node];
        float d = dinv[node];
        float t0 = d*(a0+sv.x), t1 = d*(a1+sv.y), t2 = d*(a2+sv.z);
        float g0 = 0.f, g1 = 0.f;
#pragma unroll
        for (int j = 0; j < 16; ++j) {
            float h = fmaxf(fmaf(t0, W1[j], fmaf(t1, W1[16+j], fmaf(t2, W1[32+j], b1[j]))), 0.f);
            g0 = fmaf(h, W2[2*j],   g0);
            g1 = fmaf(h, W2[2*j+1], g1);
        }
        hs2[node] = make_float2(g0 * d, g1 * d);
    }
}
__global__ void k_lay2(const unsigned* __restrict__ off, const unsigned* __restrict__ cnt,
                       const unsigned* __restrict__ ridx, const float2* __restrict__ hs2,
                       const float* __restrict__ dinv, const float* __restrict__ b2,
                       float2* __restrict__ out) {
    int lane = threadIdx.x & 15;
    int node = blockIdx.x * (blockDim.x >> 4) + (threadIdx.x >> 4);
    if (node >= NN) return;
    unsigned s = off[node], n = cnt[node];
    float a0 = 0.f, a1 = 0.f;
    for (unsigned k = lane; k < n; k += 16) {
        float2 v = hs2[ridx[s + k]];
        a0 += v.x; a1 += v.y;
    }
#pragma unroll
    for (int m = 8; m; m >>= 1) {
        a0 += __shfl_xor(a0, m); a1 += __shfl_xor(a1, m);
    }
    if (lane == 0) {
        float2 sv = hs2[node];
        float d = dinv[node];
        float z0 = d*(a0+sv.x) + b2[0];
        float z1 = d*(a1+sv.y) + b2[1];
        float mx = fmaxf(z0, z1);
        float l  = mx + logf(expf(z0 - mx) + expf(z1 - mx));
        out[node] = make_float2(z0 - l, z1 - l);
    }
}

// =================== radix tier (R11, proven) ===================
template <typename T>
__device__ __forceinline__ void phist_body(const T* __restrict__ col, long long E,
                                           unsigned* __restrict__ lcnt,
                                           unsigned short* __restrict__ cntP) {
    int r = blockIdx.x & (NRANGE - 1);
    int b = blockIdx.x >> 3;
    unsigned lo = (unsigned)r * RSZ;
    for (int i = threadIdx.x; i < RSZ; i += blockDim.x) lcnt[i] = 0u;
    __syncthreads();
    long long S = (E + NB - 1) / NB;
    long long sb = (long long)b * S, se = sb + S < E ? sb + S : E;
    long long B = blockDim.x;
    long long base = sb + threadIdx.x;
    long long nfull = (se - sb) / (4 * B);
    for (long long t = 0; t < nfull; ++t) {
        unsigned d0 = (unsigned)col[base] - lo;
        unsigned d1 = (unsigned)col[base + B] - lo;
        unsigned d2 = (unsigned)col[base + 2 * B] - lo;
        unsigned d3 = (unsigned)col[base + 3 * B] - lo;
        if (d0 < RSZ) atomicAdd(&lcnt[d0], 1u);
        if (d1 < RSZ) atomicAdd(&lcnt[d1], 1u);
        if (d2 < RSZ) atomicAdd(&lcnt[d2], 1u);
        if (d3 < RSZ) atomicAdd(&lcnt[d3], 1u);
        base += 4 * B;
    }
    for (long long e = base; e < se; e += B) {
        unsigned d = (unsigned)col[e] - lo;
        if (d < RSZ) atomicAdd(&lcnt[d], 1u);
    }
    __syncthreads();
    unsigned short* dst = cntP + (size_t)b * NN + lo;
    for (int i = threadIdx.x; i < RSZ; i += blockDim.x) dst[i] = (unsigned short)lcnt[i];
}
__global__ void k_phist(const void* ei, long long E, const int* flag,
                        unsigned short* cntP) {
    __shared__ unsigned lcnt[RSZ];
    if (*flag) phist_body(((const long long*)ei) + E, E, lcnt, cntP);
    else       phist_body(((const int*)ei) + E, E, lcnt, cntP);
}
template <typename T>
__device__ __forceinline__ void pplace_body(const T* __restrict__ ei, long long E,
                                            const unsigned* __restrict__ off,
                                            const unsigned short* __restrict__ base16,
                                            unsigned* __restrict__ lcur,
                                            unsigned* __restrict__ ridx) {
    int r = blockIdx.x & (NRANGE - 1);
    int b = blockIdx.x >> 3;
    unsigned lo = (unsigned)r * RSZ;
    const unsigned short* bb = base16 + (size_t)b * NN + lo;
    const unsigned* oo = off + lo;
    for (int i = threadIdx.x; i < RSZ; i += blockDim.x) lcur[i] = oo[i] + bb[i];
    __syncthreads();
    const T* col = ei + E;
    long long S = (E + NB - 1) / NB;
    long long sb = (long long)b * S, se = sb + S < E ? sb + S : E;
    long long B = blockDim.x;
    long long base = sb + threadIdx.x;
    long long nfull = (se - sb) / (4 * B);
    for (long long t = 0; t < nfull; ++t) {
        long long e0 = base, e1 = base + B, e2 = base + 2 * B, e3 = base + 3 * B;
        unsigned d0 = (unsigned)col[e0] - lo;
        unsigned d1 = (unsigned)col[e1] - lo;
        unsigned d2 = (unsigned)col[e2] - lo;
        unsigned d3 = (unsigned)col[e3] - lo;
        if (d0 < RSZ) { unsigned p = atomicAdd(&lcur[d0], 1u); ridx[p] = (unsigned)ei[e0]; }
        if (d1 < RSZ) { unsigned p = atomicAdd(&lcur[d1], 1u); ridx[p] = (unsigned)ei[e1]; }
        if (d2 < RSZ) { unsigned p = atomicAdd(&lcur[d2], 1u); ridx[p] = (unsigned)ei[e2]; }
        if (d3 < RSZ) { unsigned p = atomicAdd(&lcur[d3], 1u); ridx[p] = (unsigned)ei[e3]; }
        base += 4 * B;
    }
    for (long long e = base; e < se; e += B) {
        unsigned d = (unsigned)col[e] - lo;
        if (d < RSZ) { unsigned p = atomicAdd(&lcur[d], 1u); ridx[p] = (unsigned)ei[e]; }
    }
}
__global__ void k_pplace(const void* ei, long long E, const int* flag,
                         const unsigned* off, const unsigned short* base16,
                         unsigned* ridx) {
    __shared__ unsigned lcur[RSZ];
    if (*flag) pplace_body((const long long*)ei, E, off, base16, lcur, ridx);
    else       pplace_body((const int*)ei, E, off, base16, lcur, ridx);
}

// =================== B tier (R4 mid path) ===================
__global__ void k_zero(float4* z, long long n4) {
    long long stride = (long long)gridDim.x * blockDim.x;
    for (long long i = (long long)blockIdx.x * blockDim.x + threadIdx.x; i < n4; i += stride)
        z[i] = make_float4(0.f, 0.f, 0.f, 0.f);
}
template <typename T>
__device__ __forceinline__ void hist_loop(const T* __restrict__ col, long long E,
                                          unsigned* __restrict__ cnt) {
    long long stride = (long long)gridDim.x * blockDim.x;
    for (long long e = (long long)blockIdx.x * blockDim.x + threadIdx.x; e < E; e += stride)
        atomicAdd(&cnt[(unsigned)col[e]], 1u);
}
__global__ void k_histM(const void* ei, long long E, const int* flag, unsigned* cnt) {
    if (*flag) hist_loop(((const long long*)ei) + E, E, cnt);
    else       hist_loop(((const int*)ei) + E, E, cnt);
}
__global__ void k_scan3(const unsigned* __restrict__ cnt, const unsigned* __restrict__ cbase,
                        unsigned* __restrict__ off, unsigned* __restrict__ cur,
                        const float* __restrict__ x, float* __restrict__ dinv,
                        float4* __restrict__ xs) {
    int i = blockIdx.x * blockDim.x + threadIdx.x;
    if (i >= NN) return;
    unsigned o = off[i] + cbase[i >> 10];
    off[i] = o; cur[i] = o;
    float d = rsqrtf((float)cnt[i] + 1.0f);
    dinv[i] = d;
    xs[i] = make_float4(x[3*i] * d, x[3*i+1] * d, x[3*i+2] * d, 0.f);
}
template <typename T>
__device__ __forceinline__ void placeM_loop(const T* __restrict__ ei, long long E,
                                            unsigned* __restrict__ cur, unsigned* __restrict__ ridx) {
    long long stride = (long long)gridDim.x * blockDim.x;
    for (long long e = (long long)blockIdx.x * blockDim.x + threadIdx.x; e < E; e += stride) {
        unsigned c = (unsigned)ei[E + e];
        unsigned pos = atomicAdd(&cur[c], 1u);
        ridx[pos] = (unsigned)ei[e];
    }
}
__global__ void k_placeM(const void* ei, long long E, const int* flag,
                         unsigned* cur, unsigned* ridx) {
    if (*flag) placeM_loop((const long long*)ei, E, cur, ridx);
    else       placeM_loop((const int*)ei, E, cur, ridx);
}

extern "C" void kernel_launch(void* const* d_in, const int* in_sizes, int n_in,
                              void* d_out, int out_size, void* d_ws, size_t ws_size,
                              hipStream_t stream) {
    const float* x  = (const float*)d_in[0];
    const void*  ei = d_in[1];
    const float* W1 = (const float*)d_in[2];
    const float* b1 = (const float*)d_in[3];
    const float* W2 = (const float*)d_in[4];
    const float* b2 = (const float*)d_in[5];
    long long E = (long long)in_sizes[1] / 2;

    char* ws = (char*)d_ws;
    float2* out = (float2*)d_out;
    int ngrid = (NN + 255) / 256;
    int lgrid = (NN + 15) / 16;

    k_detect<<<1, 64, 0, stream>>>(ei, (int*)ws);

    if (ws_size >= SZ_S) {
        int*            flag   = (int*)(ws + S_FLAG);
        unsigned*       bcnt   = (unsigned*)(ws + S_BCNT);
        unsigned*       boff   = (unsigned*)(ws + S_BOFF);
        unsigned*       roff   = (unsigned*)(ws + S_ROFF);
        unsigned*       cnt    = (unsigned*)(ws + S_CNT);
        unsigned*       off    = (unsigned*)(ws + S_OFF);
        float*          dinv   = (float*)(ws + S_DINV);
        unsigned*       csum   = (unsigned*)(ws + S_CSUM);
        unsigned*       cbase  = (unsigned*)(ws + S_CBASE);
        float4*         xs     = (float4*)(ws + S_XS);
        float2*         hs2    = (float2*)(ws + S_HS2);
        unsigned short* base16 = (unsigned short*)(ws + S_B16);
        unsigned*       staged = (unsigned*)(ws + S_STG);
        unsigned short* cntP   = (unsigned short*)(ws + S_CNTP);
        unsigned*       ridx   = (unsigned*)(ws + S_RIDX);

        k_bcount<<<NS, 1024, 0, stream>>>(ei, E, flag, bcnt);
        k_bscan <<<1, 1024, 0, stream>>>(bcnt, boff, roff);
        k_stage <<<NS, 1024, 0, stream>>>(ei, E, flag, boff, staged);
        k_shist <<<NRANGE * NB, 1024, 0, stream>>>(staged, roff, cntP);
        k_scanA <<<NCHUNK, 256, 0, stream>>>(cntP, cnt, off, csum);
        k_scan2 <<<1, 256, 0, stream>>>(csum, cbase);
        k_final <<<ngrid, 256, 0, stream>>>(cntP, cbase, cnt, off, base16, x, dinv, xs);
        k_splace<<<NRANGE * NB, 1024, 0, stream>>>(staged, roff, off, base16, ridx);
        k_lay1  <<<lgrid, 256, 0, stream>>>(off, cnt, ridx, xs, dinv, W1, b1, W2, hs2);
        k_lay2  <<<lgrid, 256, 0, stream>>>(off, cnt, ridx, hs2, dinv, b2, out);
    } else if (ws_size >= SZ_RADIX) {
        int*            flag   = (int*)(ws + W_FLAG);
        unsigned*       cnt    = (unsigned*)(ws + W_CNT);
        unsigned*       off    = (unsigned*)(ws + W_OFF);
        float*          dinv   = (float*)(ws + W_DINV);
        unsigned*       csum   = (unsigned*)(ws + W_CSUM);
        unsigned*       cbase  = (unsigned*)(ws + W_CBASE);
        float4*         xs     = (float4*)(ws + W_XS);
        float2*         hs2    = (float2*)(ws + W_HS2);
        unsigned short* base16 = (unsigned short*)(ws + W_B16);
        unsigned short* cntP   = (unsigned short*)(ws + W_Z);
        unsigned*       ridx   = (unsigned*)(ws + W_Z);

        k_phist <<<NRANGE * NB, 1024, 0, stream>>>(ei, E, flag, cntP);
        k_scanA <<<NCHUNK, 256, 0, stream>>>(cntP, cnt, off, csum);
        k_scan2 <<<1, 256, 0, stream>>>(csum, cbase);
        k_final <<<ngrid, 256, 0, stream>>>(cntP, cbase, cnt, off, base16, x, dinv, xs);
        k_pplace<<<NRANGE * NB, 1024, 0, stream>>>(ei, E, flag, off, base16, ridx);
        k_lay1  <<<lgrid, 256, 0, stream>>>(off, cnt, ridx, xs, dinv, W1, b1, W2, hs2);
        k_lay2  <<<lgrid, 256, 0, stream>>>(off, cnt, ridx, hs2, dinv, b2, out);
    } else if (ws_size >= SZ_B) {
        int*      flag  = (int*)(ws + B_CNT - 256);
        unsigned* cnt   = (unsigned*)(ws + B_CNT);
        unsigned* off   = (unsigned*)(ws + B_OFF);
        unsigned* cur   = (unsigned*)(ws + B_CUR);
        float*    dinv  = (float*)(ws + B_DINV);
        unsigned* csum  = (unsigned*)(ws + B_CSUM);
        unsigned* cbase = (unsigned*)(ws + B_CBASE);
        float4*   xs    = (float4*)(ws + B_XS);
        float2*   hs2   = (float2*)(ws + B_HS2);
        unsigned* ridx  = (unsigned*)(ws + B_RIDX);
        long long eg = (E + 255) / 256;
        int egrid = (int)(eg > 4096 ? 4096 : eg);

        k_zero  <<<98, 256, 0, stream>>>((float4*)(ws + B_CNT), 25000);
        k_histM <<<egrid, 256, 0, stream>>>(ei, E, flag, cnt);
        k_scan1 <<<NCHUNK, 256, 0, stream>>>(cnt, off, csum);
        k_scan2 <<<1, 256, 0, stream>>>(csum, cbase);
        k_scan3 <<<ngrid, 256, 0, stream>>>(cnt, cbase, off, cur, x, dinv, xs);
        k_placeM<<<egrid, 256, 0, stream>>>(ei, E, flag, cur, ridx);
        k_lay1  <<<lgrid, 256, 0, stream>>>(off, cnt, ridx, xs, dinv, W1, b1, W2, hs2);
        k_lay2  <<<lgrid, 256, 0, stream>>>(off, cnt, ridx, hs2, dinv, b2, out);
    }
}